// Round 1
// baseline (8981.272 us; speedup 1.0000x reference)
//
#include <hip/hip_runtime.h>
#include <hip/hip_bf16.h>

// Problem constants
#define BATCH 8
#define SEQL 1024
#define INDIM 4096
#define HDIM 768
#define DI 500
#define NSTATE 16
#define RRANK 48
#define KCONV 4
#define NLAYER 5
#define BL (BATCH * SEQL)   // 8192

// ---------------------------------------------------------------------------
// Generic guarded fp32 GEMM: C(M,N) = A(M,K) @ B(K,N)  [+ epilogue]
// EPI 0: store; EPI 1: C += result (residual accumulate);
// EPI 2: softplus(result + bias) (dt path)
// 64x64 tile, BK=16, 256 threads, 4x4 microtile per thread.
// ---------------------------------------------------------------------------
template <int EPI>
__global__ __launch_bounds__(256) void gemm_f32(
    const float* __restrict__ A, const float* __restrict__ B,
    float* __restrict__ C, const float* __restrict__ bias,
    int M, int N, int K, int lda, int ldb, int ldc) {
  __shared__ float As[16][65];
  __shared__ float Bs[16][65];
  const int tx = threadIdx.x, ty = threadIdx.y;
  const int tid = ty * 16 + tx;
  const int m0 = blockIdx.y * 64, n0 = blockIdx.x * 64;
  float acc[4][4] = {};
  const int ntk = (K + 15) / 16;
  for (int kt = 0; kt < ntk; ++kt) {
    const int k0 = kt * 16;
#pragma unroll
    for (int l = 0; l < 4; ++l) {
      int e = tid + l * 256;
      int ar = e >> 4, ak = e & 15;
      int gr = m0 + ar, gk = k0 + ak;
      As[ak][ar] = (gr < M && gk < K) ? A[(long)gr * lda + gk] : 0.f;
    }
#pragma unroll
    for (int l = 0; l < 4; ++l) {
      int e = tid + l * 256;
      int bk = e >> 6, bc = e & 63;
      int gk = k0 + bk, gc = n0 + bc;
      Bs[bk][bc] = (gk < K && gc < N) ? B[(long)gk * ldb + gc] : 0.f;
    }
    __syncthreads();
#pragma unroll
    for (int kk = 0; kk < 16; ++kk) {
      float av[4], bv[4];
#pragma unroll
      for (int i = 0; i < 4; ++i) av[i] = As[kk][ty * 4 + i];
#pragma unroll
      for (int j = 0; j < 4; ++j) bv[j] = Bs[kk][tx * 4 + j];
#pragma unroll
      for (int i = 0; i < 4; ++i)
#pragma unroll
        for (int j = 0; j < 4; ++j) acc[i][j] += av[i] * bv[j];
    }
    __syncthreads();
  }
#pragma unroll
  for (int i = 0; i < 4; ++i) {
    int r = m0 + ty * 4 + i;
    if (r >= M) continue;
#pragma unroll
    for (int j = 0; j < 4; ++j) {
      int c = n0 + tx * 4 + j;
      if (c >= N) continue;
      float v = acc[i][j];
      if (EPI == 1) v += C[(long)r * ldc + c];
      if (EPI == 2) {
        v += bias[c];
        v = (v > 15.f) ? v : log1pf(expf(v));
      }
      C[(long)r * ldc + c] = v;
    }
  }
}

// ---------------------------------------------------------------------------
// Block reduce (blockDim == 256)
// ---------------------------------------------------------------------------
__device__ __forceinline__ float block_sum256(float v, float* sm) {
#pragma unroll
  for (int off = 32; off > 0; off >>= 1) v += __shfl_down(v, off, 64);
  int wid = threadIdx.x >> 6;
  if ((threadIdx.x & 63) == 0) sm[wid] = v;
  __syncthreads();
  float t = sm[0] + sm[1] + sm[2] + sm[3];
  __syncthreads();
  return t;
}

// ---------------------------------------------------------------------------
// RMSNorm over H=768: one block per row, 256 threads x 3 elems
// ---------------------------------------------------------------------------
__global__ __launch_bounds__(256) void rmsnorm_kernel(
    const float* __restrict__ X, const float* __restrict__ w,
    float* __restrict__ XN) {
  __shared__ float sm[4];
  const long row = blockIdx.x;
  const float* x = X + row * HDIM;
  float vals[3];
  float s = 0.f;
#pragma unroll
  for (int j = 0; j < 3; ++j) {
    vals[j] = x[threadIdx.x + j * 256];
    s += vals[j] * vals[j];
  }
  float tot = block_sum256(s, sm);
  float scale = rsqrtf(tot / (float)HDIM + 1e-5f);
#pragma unroll
  for (int j = 0; j < 3; ++j) {
    int c = threadIdx.x + j * 256;
    XN[row * HDIM + c] = vals[j] * scale * w[c];
  }
}

// ---------------------------------------------------------------------------
// Causal depthwise conv (K=4) + SiLU.  u_raw = PROJ[:, 0:500]
// ---------------------------------------------------------------------------
__global__ __launch_bounds__(256) void conv_silu_kernel(
    const float* __restrict__ PROJ, const float* __restrict__ cw,
    const float* __restrict__ cb, float* __restrict__ U, int layer) {
  long idx = (long)blockIdx.x * 256 + threadIdx.x;
  if (idx >= (long)BL * DI) return;
  int d = (int)(idx % DI);
  long row = idx / DI;
  int t = (int)(row % SEQL);
  const float* w = cw + ((long)layer * DI + d) * KCONV;
  float acc = cb[layer * DI + d];
#pragma unroll
  for (int k = 0; k < KCONV; ++k) {
    int tt = t + k - (KCONV - 1);
    if (tt >= 0) acc += PROJ[(row + k - (KCONV - 1)) * 1000 + d] * w[k];
  }
  U[idx] = acc / (1.f + expf(-acc));  // silu
}

// ---------------------------------------------------------------------------
// Sequential SSM scan. 16 lanes per (b,d) pair (lane = state index n).
// Computes y = scan(...) + u*Dp, then y *= silu(gate); writes over DT (in place).
// ---------------------------------------------------------------------------
__global__ __launch_bounds__(256) void scan_kernel(
    const float* __restrict__ SSM, float* __restrict__ DT,
    const float* __restrict__ U, const float* __restrict__ PROJ,
    const float* __restrict__ A_log, const float* __restrict__ Dparam,
    int layer) {
  const int grp = threadIdx.x >> 4;       // 16 groups / block
  const int n = threadIdx.x & 15;         // state index
  const int pair = blockIdx.x * 16 + grp; // (b,d) pair, 4000 total
  if (pair >= BATCH * DI) return;
  const int b = pair / DI;
  const int d = pair % DI;
  const float An = -expf(A_log[((long)layer * DI + d) * NSTATE + n]);
  const float Dp = Dparam[layer * DI + d];
  float h = 0.f;
  for (int t = 0; t < SEQL; ++t) {
    const long row = (long)b * SEQL + t;
    const float dt = DT[row * DI + d];
    const float u = U[row * DI + d];
    const float Bn = SSM[row * 80 + RRANK + n];
    const float Cn = SSM[row * 80 + RRANK + NSTATE + n];
    h = __expf(dt * An) * h + dt * Bn * u;
    float p = h * Cn;
    p += __shfl_xor(p, 1, 64);
    p += __shfl_xor(p, 2, 64);
    p += __shfl_xor(p, 4, 64);
    p += __shfl_xor(p, 8, 64);
    if (n == 0) {
      float gate = PROJ[row * 1000 + DI + d];
      float y = p + u * Dp;
      y *= gate / (1.f + expf(-gate));
      DT[row * DI + d] = y;  // Y in place over DT (already consumed this t)
    }
  }
}

// ---------------------------------------------------------------------------
// Final: rmsnorm(last token) then dot with W_cls -> logits[b]
// ---------------------------------------------------------------------------
__global__ __launch_bounds__(256) void final_kernel(
    const float* __restrict__ X, const float* __restrict__ nfw,
    const float* __restrict__ Wcls, float* __restrict__ out) {
  __shared__ float sm[4];
  const int b = blockIdx.x;
  const long row = (long)b * SEQL + (SEQL - 1);
  const float* x = X + row * HDIM;
  float vals[3];
  float s = 0.f;
#pragma unroll
  for (int j = 0; j < 3; ++j) {
    vals[j] = x[threadIdx.x + j * 256];
    s += vals[j] * vals[j];
  }
  float tot = block_sum256(s, sm);
  float scale = rsqrtf(tot / (float)HDIM + 1e-5f);
  float dot = 0.f;
#pragma unroll
  for (int j = 0; j < 3; ++j) {
    int c = threadIdx.x + j * 256;
    dot += vals[j] * scale * nfw[c] * Wcls[c];
  }
  float td = block_sum256(dot, sm);
  if (threadIdx.x == 0) out[b] = td;
}

// ---------------------------------------------------------------------------
extern "C" void kernel_launch(void* const* d_in, const int* in_sizes, int n_in,
                              void* d_out, int out_size, void* d_ws,
                              size_t ws_size, hipStream_t stream) {
  const float* inputs  = (const float*)d_in[0];
  const float* W_down  = (const float*)d_in[1];
  const float* in_proj = (const float*)d_in[2];
  const float* conv_w  = (const float*)d_in[3];
  const float* conv_b  = (const float*)d_in[4];
  const float* x_proj  = (const float*)d_in[5];
  const float* dt_w    = (const float*)d_in[6];
  const float* dt_b    = (const float*)d_in[7];
  const float* A_log   = (const float*)d_in[8];
  const float* D_param = (const float*)d_in[9];
  const float* out_w   = (const float*)d_in[10];
  const float* norm_w  = (const float*)d_in[11];
  const float* norm_fw = (const float*)d_in[12];
  const float* W_cls   = (const float*)d_in[13];
  float* out = (float*)d_out;

  float* ws  = (float*)d_ws;
  float* X    = ws;                     // 8192*768
  float* XN   = X + (long)BL * HDIM;    // 8192*768
  float* PROJ = XN + (long)BL * HDIM;   // 8192*1000
  float* U    = PROJ + (long)BL * 1000; // 8192*500
  float* SSM  = U + (long)BL * DI;      // 8192*80
  float* DT   = SSM + (long)BL * 80;    // 8192*500 (also Y, in place)

  dim3 blk(16, 16);

  // X = inputs @ W_down   (8192 x 4096 x 768)
  gemm_f32<0><<<dim3(HDIM / 64, BL / 64), blk, 0, stream>>>(
      inputs, W_down, X, nullptr, BL, HDIM, INDIM, INDIM, HDIM, HDIM);

  for (int i = 0; i < NLAYER; ++i) {
    // XN = rmsnorm(X, norm_w[i])
    rmsnorm_kernel<<<BL, 256, 0, stream>>>(X, norm_w + i * HDIM, XN);
    // PROJ = XN @ in_proj[i]   (8192 x 768 x 1000)
    gemm_f32<0><<<dim3((1000 + 63) / 64, BL / 64), blk, 0, stream>>>(
        XN, in_proj + (long)i * HDIM * 1000, PROJ, nullptr, BL, 1000, HDIM,
        HDIM, 1000, 1000);
    // U = silu(conv(PROJ[:, :500]))
    conv_silu_kernel<<<((long)BL * DI + 255) / 256, 256, 0, stream>>>(
        PROJ, conv_w, conv_b, U, i);
    // SSM = U @ x_proj[i]   (8192 x 500 x 80)
    gemm_f32<0><<<dim3(2, BL / 64), blk, 0, stream>>>(
        U, x_proj + (long)i * DI * 80, SSM, nullptr, BL, 80, DI, DI, 80, 80);
    // DT = softplus(SSM[:, :48] @ dt_w[i] + dt_b[i])   (8192 x 48 x 500)
    gemm_f32<2><<<dim3((DI + 63) / 64, BL / 64), blk, 0, stream>>>(
        SSM, dt_w + (long)i * RRANK * DI, DT, dt_b + i * DI, BL, DI, RRANK,
        80, DI, DI);
    // scan -> Y (in place over DT), fused +u*Dp and silu(gate) multiply
    scan_kernel<<<(BATCH * DI + 15) / 16, 256, 0, stream>>>(
        SSM, DT, U, PROJ, A_log, D_param, i);
    // X += Y @ out_w[i]   (8192 x 500 x 768)
    gemm_f32<1><<<dim3(HDIM / 64, BL / 64), blk, 0, stream>>>(
        DT, out_w + (long)i * DI * HDIM, X, nullptr, BL, HDIM, DI, DI, HDIM,
        HDIM);
  }

  // logits
  final_kernel<<<BATCH, 256, 0, stream>>>(X, norm_fw, W_cls, out);
}

// Round 2
// 4719.171 us; speedup vs baseline: 1.9031x; 1.9031x over previous
//
#include <hip/hip_runtime.h>
#include <hip/hip_bf16.h>

// Problem constants
#define BATCH 8
#define SEQL 1024
#define INDIM 4096
#define HDIM 768
#define DI 500
#define NSTATE 16
#define RRANK 48
#define KCONV 4
#define NLAYER 5
#define BL (BATCH * SEQL)  // 8192

typedef __attribute__((ext_vector_type(8))) short bf16x8;
typedef __attribute__((ext_vector_type(4))) float f32x4;

__device__ __forceinline__ void gl_lds16(const void* g, void* l) {
  __builtin_amdgcn_global_load_lds(
      (const __attribute__((address_space(1))) void*)g,
      (__attribute__((address_space(3))) void*)l, 16, 0, 0);
}

// ---------------------------------------------------------------------------
// bf16 MFMA GEMM: C(M,N) fp32 = A(M,K)bf16 @ Bt(N,K)bf16^T  [+ epilogue]
// A row-major [M][lda], Bt row-major [Npad][ldb] (transposed weight).
// 128x128 tile, BK=32, 256 threads = 4 waves (2x2 of 64x64), m97 structure.
// EPI 0: store; EPI 1: C += ; EPI 2: softplus(v + bias[col])
// M must be multiple of 128; grid.x covers Npad/128; epilogue guards col<N.
// ---------------------------------------------------------------------------
template <int EPI>
__global__ __launch_bounds__(256) void gemm_mfma(
    const short* __restrict__ A, const short* __restrict__ Bt,
    float* __restrict__ C, const float* __restrict__ bias,
    int M, int N, int K, int lda, int ldb, int ldc) {
  __shared__ short As[128 * 32];
  __shared__ short Bs[128 * 32];
  const int tid = threadIdx.x;
  const int w = tid >> 6, lane = tid & 63;
  const int m0 = blockIdx.y * 128, n0 = blockIdx.x * 128;
  const int wr = w >> 1, wc = w & 1;
  f32x4 acc[4][4] = {};

  const int srow = tid >> 2;       // 0..63
  const int scol = (tid & 3) * 8;  // elem in K
  const short* ga0 = A + (size_t)(m0 + srow) * lda + scol;
  const short* ga1 = A + (size_t)(m0 + 64 + srow) * lda + scol;
  const short* gb0 = Bt + (size_t)(n0 + srow) * ldb + scol;
  const short* gb1 = Bt + (size_t)(n0 + 64 + srow) * ldb + scol;
  short* lA0 = As + w * 512;         // wave-uniform; HW adds lane*16B
  short* lA1 = As + 2048 + w * 512;
  short* lB0 = Bs + w * 512;
  short* lB1 = Bs + 2048 + w * 512;
  const int lr = lane & 15, kb = lane >> 4;

  for (int k0 = 0; k0 < K; k0 += 32) {
    gl_lds16(ga0, lA0);
    gl_lds16(ga1, lA1);
    gl_lds16(gb0, lB0);
    gl_lds16(gb1, lB1);
    ga0 += 32; ga1 += 32; gb0 += 32; gb1 += 32;
    __syncthreads();  // compiler drains vmcnt(0) before barrier
    bf16x8 af[4], bfr[4];
#pragma unroll
    for (int i = 0; i < 4; ++i) {
      af[i] = *(const bf16x8*)(As + (wr * 64 + i * 16 + lr) * 32 + kb * 8);
      bfr[i] = *(const bf16x8*)(Bs + (wc * 64 + i * 16 + lr) * 32 + kb * 8);
    }
#pragma unroll
    for (int i = 0; i < 4; ++i)
#pragma unroll
      for (int j = 0; j < 4; ++j)
        acc[i][j] = __builtin_amdgcn_mfma_f32_16x16x32_bf16(af[i], bfr[j],
                                                            acc[i][j], 0, 0, 0);
    __syncthreads();
  }

  // C/D layout (m89): col = lane&15, row = (lane>>4)*4 + reg
#pragma unroll
  for (int i = 0; i < 4; ++i) {
    const int row = m0 + wr * 64 + i * 16 + (lane >> 4) * 4;
#pragma unroll
    for (int j = 0; j < 4; ++j) {
      const int col = n0 + wc * 64 + j * 16 + (lane & 15);
      if (col < N) {
#pragma unroll
        for (int r = 0; r < 4; ++r) {
          float v = acc[i][j][r];
          size_t idx = (size_t)(row + r) * ldc + col;
          if (EPI == 1) v += C[idx];
          if (EPI == 2) {
            v += bias[col];
            v = (v > 15.f) ? v : log1pf(expf(v));
          }
          C[idx] = v;
        }
      }
    }
  }
}

// ---------------------------------------------------------------------------
// fp32 -> bf16 elementwise cast (vectorized x4)
// ---------------------------------------------------------------------------
__global__ __launch_bounds__(256) void convert_cast(
    const float* __restrict__ src, __hip_bfloat16* __restrict__ dst, long n) {
  long i = ((long)blockIdx.x * 256 + threadIdx.x) * 4;
  if (i >= n) return;
  float4 v = *(const float4*)(src + i);
  dst[i + 0] = __float2bfloat16(v.x);
  dst[i + 1] = __float2bfloat16(v.y);
  dst[i + 2] = __float2bfloat16(v.z);
  dst[i + 3] = __float2bfloat16(v.w);
}

// ---------------------------------------------------------------------------
// Weight convert + transpose + pad:  src fp32 [K][N] -> dst bf16 [Npad][Kpad]
// grid.y = layer
// ---------------------------------------------------------------------------
__global__ __launch_bounds__(256) void convert_wT(
    const float* __restrict__ src, __hip_bfloat16* __restrict__ dst, int K,
    int N, int Kpad, int Npad, long src_lstride, long dst_lstride) {
  int idx = blockIdx.x * 256 + threadIdx.x;
  int per = Kpad * Npad;
  if (idx >= per) return;
  const float* s = src + (long)blockIdx.y * src_lstride;
  __hip_bfloat16* d = dst + (long)blockIdx.y * dst_lstride;
  int n = idx / Kpad, k = idx % Kpad;
  float v = (k < K && n < N) ? s[(long)k * N + n] : 0.f;
  d[idx] = __float2bfloat16(v);
}

// ---------------------------------------------------------------------------
// Block reduce (blockDim == 256)
// ---------------------------------------------------------------------------
__device__ __forceinline__ float block_sum256(float v, float* sm) {
#pragma unroll
  for (int off = 32; off > 0; off >>= 1) v += __shfl_down(v, off, 64);
  int wid = threadIdx.x >> 6;
  if ((threadIdx.x & 63) == 0) sm[wid] = v;
  __syncthreads();
  float t = sm[0] + sm[1] + sm[2] + sm[3];
  __syncthreads();
  return t;
}

// ---------------------------------------------------------------------------
// RMSNorm over H=768 -> bf16 out. one block per row
// ---------------------------------------------------------------------------
__global__ __launch_bounds__(256) void rmsnorm_kernel(
    const float* __restrict__ X, const float* __restrict__ w,
    __hip_bfloat16* __restrict__ XN) {
  __shared__ float sm[4];
  const long row = blockIdx.x;
  const float* x = X + row * HDIM;
  float vals[3];
  float s = 0.f;
#pragma unroll
  for (int j = 0; j < 3; ++j) {
    vals[j] = x[threadIdx.x + j * 256];
    s += vals[j] * vals[j];
  }
  float tot = block_sum256(s, sm);
  float scale = rsqrtf(tot / (float)HDIM + 1e-5f);
#pragma unroll
  for (int j = 0; j < 3; ++j) {
    int c = threadIdx.x + j * 256;
    XN[row * HDIM + c] = __float2bfloat16(vals[j] * scale * w[c]);
  }
}

// ---------------------------------------------------------------------------
// Causal depthwise conv (K=4) + SiLU -> bf16 U [BL][512], pad cols zeroed
// ---------------------------------------------------------------------------
__global__ __launch_bounds__(256) void conv_silu_kernel(
    const float* __restrict__ PROJ, const float* __restrict__ cw,
    const float* __restrict__ cb, __hip_bfloat16* __restrict__ U, int layer) {
  long idx = (long)blockIdx.x * 256 + threadIdx.x;
  if (idx >= (long)BL * 512) return;
  int d = (int)(idx & 511);
  long row = idx >> 9;
  if (d >= DI) {
    U[idx] = __float2bfloat16(0.f);
    return;
  }
  int t = (int)(row & (SEQL - 1));
  const float* w = cw + ((long)layer * DI + d) * KCONV;
  float acc = cb[layer * DI + d];
#pragma unroll
  for (int k = 0; k < KCONV; ++k) {
    int tt = t + k - (KCONV - 1);
    if (tt >= 0) acc += PROJ[(row + k - (KCONV - 1)) * 1000 + d] * w[k];
  }
  U[idx] = __float2bfloat16(acc / (1.f + expf(-acc)));  // silu
}

// ---------------------------------------------------------------------------
// SSM[:, :48] fp32 -> bf16 [BL][64] (cols 48..63 = 0)
// ---------------------------------------------------------------------------
__global__ __launch_bounds__(256) void dtconv_kernel(
    const float* __restrict__ SSM, __hip_bfloat16* __restrict__ SSMbf) {
  long idx = (long)blockIdx.x * 256 + threadIdx.x;
  if (idx >= (long)BL * 64) return;
  int c = (int)(idx & 63);
  long row = idx >> 6;
  float v = (c < RRANK) ? SSM[row * 128 + c] : 0.f;
  SSMbf[idx] = __float2bfloat16(v);
}

// ---------------------------------------------------------------------------
// Sequential SSM scan. 16 lanes per (b,d). Writes Ybf bf16 [BL][512].
// ---------------------------------------------------------------------------
__global__ __launch_bounds__(256) void scan_kernel(
    const float* __restrict__ SSM, const float* __restrict__ DT,
    const __hip_bfloat16* __restrict__ U, const float* __restrict__ PROJ,
    const float* __restrict__ A_log, const float* __restrict__ Dparam,
    __hip_bfloat16* __restrict__ Y, int layer) {
  const int grp = threadIdx.x >> 4;
  const int n = threadIdx.x & 15;
  const int pair = blockIdx.x * 16 + grp;
  if (pair >= BATCH * DI) return;
  const int b = pair / DI;
  const int d = pair % DI;
  const float An = -expf(A_log[((long)layer * DI + d) * NSTATE + n]);
  const float Dp = Dparam[layer * DI + d];
  float h = 0.f;
  for (int t = 0; t < SEQL; ++t) {
    const long row = (long)b * SEQL + t;
    const float dt = DT[row * DI + d];
    const float u = __bfloat162float(U[row * 512 + d]);
    const float Bn = SSM[row * 128 + RRANK + n];
    const float Cn = SSM[row * 128 + RRANK + NSTATE + n];
    h = __expf(dt * An) * h + dt * Bn * u;
    float p = h * Cn;
    p += __shfl_xor(p, 1, 64);
    p += __shfl_xor(p, 2, 64);
    p += __shfl_xor(p, 4, 64);
    p += __shfl_xor(p, 8, 64);
    if (n == 0) {
      float gate = PROJ[row * 1000 + DI + d];
      float y = p + u * Dp;
      y *= gate / (1.f + expf(-gate));
      Y[row * 512 + d] = __float2bfloat16(y);
    }
  }
}

// ---------------------------------------------------------------------------
// Final: rmsnorm(last token) dot W_cls
// ---------------------------------------------------------------------------
__global__ __launch_bounds__(256) void final_kernel(
    const float* __restrict__ X, const float* __restrict__ nfw,
    const float* __restrict__ Wcls, float* __restrict__ out) {
  __shared__ float sm[4];
  const int b = blockIdx.x;
  const long row = (long)b * SEQL + (SEQL - 1);
  const float* x = X + row * HDIM;
  float vals[3];
  float s = 0.f;
#pragma unroll
  for (int j = 0; j < 3; ++j) {
    vals[j] = x[threadIdx.x + j * 256];
    s += vals[j] * vals[j];
  }
  float tot = block_sum256(s, sm);
  float scale = rsqrtf(tot / (float)HDIM + 1e-5f);
  float dot = 0.f;
#pragma unroll
  for (int j = 0; j < 3; ++j) {
    int c = threadIdx.x + j * 256;
    dot += vals[j] * scale * nfw[c] * Wcls[c];
  }
  float td = block_sum256(dot, sm);
  if (threadIdx.x == 0) out[b] = td;
}

// ---------------------------------------------------------------------------
extern "C" void kernel_launch(void* const* d_in, const int* in_sizes, int n_in,
                              void* d_out, int out_size, void* d_ws,
                              size_t ws_size, hipStream_t stream) {
  const float* inputs  = (const float*)d_in[0];
  const float* W_down  = (const float*)d_in[1];
  const float* in_proj = (const float*)d_in[2];
  const float* conv_w  = (const float*)d_in[3];
  const float* conv_b  = (const float*)d_in[4];
  const float* x_proj  = (const float*)d_in[5];
  const float* dt_w    = (const float*)d_in[6];
  const float* dt_b    = (const float*)d_in[7];
  const float* A_log   = (const float*)d_in[8];
  const float* D_param = (const float*)d_in[9];
  const float* out_w   = (const float*)d_in[10];
  const float* norm_w  = (const float*)d_in[11];
  const float* norm_fw = (const float*)d_in[12];
  const float* W_cls   = (const float*)d_in[13];
  float* out = (float*)d_out;

  char* ws = (char*)d_ws;
  // Region A (aliased): init phase holds Abf+Wdbf; layer phase holds the rest.
  __hip_bfloat16* Abf   = (__hip_bfloat16*)(ws + 0);          // 8192*4096*2 = 67108864
  __hip_bfloat16* Wdbf  = (__hip_bfloat16*)(ws + 67108864);   // 768*4096*2  = 6291456
  __hip_bfloat16* XNbf  = (__hip_bfloat16*)(ws + 0);          // 8192*768*2  (aliases DT)
  float*          DT    = (float*)(ws + 0);                   // 8192*500*4 = 16384000
  float*          PROJ  = (float*)(ws + 16384000);            // 8192*1000*4 = 32768000
  float*          SSM   = (float*)(ws + 49152000);            // 8192*128*4 = 4194304
  __hip_bfloat16* SSMbf = (__hip_bfloat16*)(ws + 53346304);   // 8192*64*2 = 1048576
  __hip_bfloat16* Ubf   = (__hip_bfloat16*)(ws + 54394880);   // 8192*512*2 = 8388608
  __hip_bfloat16* Ybf   = (__hip_bfloat16*)(ws + 62783488);   // 8388608 (ends 71172096)
  // Persistent region
  float*          X     = (float*)(ws + 73400320);            // 8192*768*4 = 25165824
  __hip_bfloat16* inpbf = (__hip_bfloat16*)(ws + 98566144);   // 5*1024*768*2 = 7864320
  __hip_bfloat16* xpbf  = (__hip_bfloat16*)(ws + 106430464);  // 5*128*512*2 = 655360
  __hip_bfloat16* dtwbf = (__hip_bfloat16*)(ws + 107085824);  // 5*512*64*2 = 327680
  __hip_bfloat16* outwbf= (__hip_bfloat16*)(ws + 107413504);  // 5*768*512*2 = 3932160

  // --- init: conversions ---
  convert_cast<<<(long)BL * 4096 / 4 / 256, 256, 0, stream>>>(inputs, Abf,
                                                              (long)BL * 4096);
  convert_wT<<<dim3((768 * 4096 + 255) / 256, 1), 256, 0, stream>>>(
      W_down, Wdbf, 4096, 768, 4096, 768, 0, 0);
  convert_wT<<<dim3((1024 * 768 + 255) / 256, NLAYER), 256, 0, stream>>>(
      in_proj, inpbf, 768, 1000, 768, 1024, (long)HDIM * 1000, 1024 * 768);
  convert_wT<<<dim3((128 * 512 + 255) / 256, NLAYER), 256, 0, stream>>>(
      x_proj, xpbf, 500, 80, 512, 128, (long)DI * 80, 128 * 512);
  convert_wT<<<dim3((512 * 64 + 255) / 256, NLAYER), 256, 0, stream>>>(
      dt_w, dtwbf, 48, 500, 64, 512, (long)RRANK * DI, 512 * 64);
  convert_wT<<<dim3((768 * 512 + 255) / 256, NLAYER), 256, 0, stream>>>(
      out_w, outwbf, 500, 768, 512, 768, (long)DI * HDIM, 768 * 512);

  // X = inputs @ W_down   (8192 x 768 x 4096)
  gemm_mfma<0><<<dim3(768 / 128, BL / 128), 256, 0, stream>>>(
      (const short*)Abf, (const short*)Wdbf, X, nullptr, BL, HDIM, INDIM,
      INDIM, INDIM, HDIM);

  // Ybf pads must be zero before first out_w GEMM (region aliased with Abf)
  hipMemsetAsync(Ybf, 0, (size_t)BL * 512 * 2, stream);

  for (int i = 0; i < NLAYER; ++i) {
    rmsnorm_kernel<<<BL, 256, 0, stream>>>(X, norm_w + i * HDIM, XNbf);
    // PROJ = XN @ in_proj[i]   (8192 x 1000 x 768)
    gemm_mfma<0><<<dim3(1024 / 128, BL / 128), 256, 0, stream>>>(
        (const short*)XNbf, (const short*)(inpbf + (long)i * 1024 * 768), PROJ,
        nullptr, BL, 1000, HDIM, HDIM, HDIM, 1000);
    conv_silu_kernel<<<(long)BL * 512 / 256, 256, 0, stream>>>(
        PROJ, conv_w, conv_b, Ubf, i);
    // SSM = U @ x_proj[i]   (8192 x 80 x 500pad512)
    gemm_mfma<0><<<dim3(1, BL / 128), 256, 0, stream>>>(
        (const short*)Ubf, (const short*)(xpbf + (long)i * 128 * 512), SSM,
        nullptr, BL, 80, 512, 512, 512, 128);
    dtconv_kernel<<<(long)BL * 64 / 256, 256, 0, stream>>>(SSM, SSMbf);
    // DT = softplus(SSM[:,:48] @ dt_w[i] + dt_b[i])   (8192 x 500 x 48pad64)
    gemm_mfma<2><<<dim3(512 / 128, BL / 128), 256, 0, stream>>>(
        (const short*)SSMbf, (const short*)(dtwbf + (long)i * 512 * 64), DT,
        dt_b + i * DI, BL, DI, 64, 64, 64, DI);
    scan_kernel<<<(BATCH * DI + 15) / 16, 256, 0, stream>>>(
        SSM, DT, Ubf, PROJ, A_log, D_param, Ybf, i);
    // X += Y @ out_w[i]   (8192 x 768 x 500pad512)
    gemm_mfma<1><<<dim3(768 / 128, BL / 128), 256, 0, stream>>>(
        (const short*)Ybf, (const short*)(outwbf + (long)i * 768 * 512), X,
        nullptr, BL, HDIM, 512, 512, 512, HDIM);
  }

  final_kernel<<<BATCH, 256, 0, stream>>>(X, norm_fw, W_cls, out);
}

// Round 3
// 1380.968 us; speedup vs baseline: 6.5036x; 3.4173x over previous
//
#include <hip/hip_runtime.h>
#include <hip/hip_bf16.h>

// Problem constants
#define BATCH 8
#define SEQL 1024
#define INDIM 4096
#define HDIM 768
#define DI 500
#define NSTATE 16
#define RRANK 48
#define KCONV 4
#define NLAYER 5
#define BL (BATCH * SEQL)  // 8192

typedef __attribute__((ext_vector_type(8))) short bf16x8;
typedef __attribute__((ext_vector_type(4))) float f32x4;

__device__ __forceinline__ void gl_lds16(const void* g, void* l) {
  __builtin_amdgcn_global_load_lds(
      (const __attribute__((address_space(1))) void*)g,
      (__attribute__((address_space(3))) void*)l, 16, 0, 0);
}

// ---------------------------------------------------------------------------
// bf16 MFMA GEMM: C(M,N) fp32 = A(M,K)bf16 @ Bt(N,K)bf16^T  [+ epilogue]
// 128x128 tile, BK=32, 256 threads = 4 waves (2x2 of 64x64), m97 structure.
// EPI 0: store; EPI 1: C += ; EPI 2: softplus(v+bias[col]);
// EPI 3: softplus(v+bias[col]) stored TRANSPOSED to C=[b][col][t] (DTt layout)
// ---------------------------------------------------------------------------
template <int EPI>
__global__ __launch_bounds__(256) void gemm_mfma(
    const short* __restrict__ A, const short* __restrict__ Bt,
    float* __restrict__ C, const float* __restrict__ bias,
    int M, int N, int K, int lda, int ldb, int ldc) {
  __shared__ short As[128 * 32];
  __shared__ short Bs[128 * 32];
  const int tid = threadIdx.x;
  const int w = tid >> 6, lane = tid & 63;
  const int m0 = blockIdx.y * 128, n0 = blockIdx.x * 128;
  const int wr = w >> 1, wc = w & 1;
  f32x4 acc[4][4] = {};

  const int srow = tid >> 2;
  const int scol = (tid & 3) * 8;
  const short* ga0 = A + (size_t)(m0 + srow) * lda + scol;
  const short* ga1 = A + (size_t)(m0 + 64 + srow) * lda + scol;
  const short* gb0 = Bt + (size_t)(n0 + srow) * ldb + scol;
  const short* gb1 = Bt + (size_t)(n0 + 64 + srow) * ldb + scol;
  short* lA0 = As + w * 512;
  short* lA1 = As + 2048 + w * 512;
  short* lB0 = Bs + w * 512;
  short* lB1 = Bs + 2048 + w * 512;
  const int lr = lane & 15, kb = lane >> 4;

  for (int k0 = 0; k0 < K; k0 += 32) {
    gl_lds16(ga0, lA0);
    gl_lds16(ga1, lA1);
    gl_lds16(gb0, lB0);
    gl_lds16(gb1, lB1);
    ga0 += 32; ga1 += 32; gb0 += 32; gb1 += 32;
    __syncthreads();
    bf16x8 af[4], bfr[4];
#pragma unroll
    for (int i = 0; i < 4; ++i) {
      af[i] = *(const bf16x8*)(As + (wr * 64 + i * 16 + lr) * 32 + kb * 8);
      bfr[i] = *(const bf16x8*)(Bs + (wc * 64 + i * 16 + lr) * 32 + kb * 8);
    }
#pragma unroll
    for (int i = 0; i < 4; ++i)
#pragma unroll
      for (int j = 0; j < 4; ++j)
        acc[i][j] = __builtin_amdgcn_mfma_f32_16x16x32_bf16(af[i], bfr[j],
                                                            acc[i][j], 0, 0, 0);
    __syncthreads();
  }

  // C/D layout (m89): col = lane&15, row = (lane>>4)*4 + reg
#pragma unroll
  for (int i = 0; i < 4; ++i) {
    const int row = m0 + wr * 64 + i * 16 + (lane >> 4) * 4;
#pragma unroll
    for (int j = 0; j < 4; ++j) {
      const int col = n0 + wc * 64 + j * 16 + (lane & 15);
      if (col < N) {
        if (EPI == 3) {
          float4 v4;
#pragma unroll
          for (int r = 0; r < 4; ++r) {
            float v = acc[i][j][r] + bias[col];
            ((float*)&v4)[r] = (v > 15.f) ? v : log1pf(expf(v));
          }
          const int bb = row >> 10, tt = row & 1023;
          *(float4*)&C[((size_t)bb * DI + col) * 1024 + tt] = v4;
        } else {
#pragma unroll
          for (int r = 0; r < 4; ++r) {
            float v = acc[i][j][r];
            size_t idx = (size_t)(row + r) * ldc + col;
            if (EPI == 1) v += C[idx];
            if (EPI == 2) {
              v += bias[col];
              v = (v > 15.f) ? v : log1pf(expf(v));
            }
            C[idx] = v;
          }
        }
      }
    }
  }
}

// ---------------------------------------------------------------------------
// fp32 -> bf16 cast
// ---------------------------------------------------------------------------
__global__ __launch_bounds__(256) void convert_cast(
    const float* __restrict__ src, __hip_bfloat16* __restrict__ dst, long n) {
  long i = ((long)blockIdx.x * 256 + threadIdx.x) * 4;
  if (i >= n) return;
  float4 v = *(const float4*)(src + i);
  dst[i + 0] = __float2bfloat16(v.x);
  dst[i + 1] = __float2bfloat16(v.y);
  dst[i + 2] = __float2bfloat16(v.z);
  dst[i + 3] = __float2bfloat16(v.w);
}

// ---------------------------------------------------------------------------
// Weight convert + transpose + pad: src fp32 [K][N] -> dst bf16 [Npad][Kpad]
// ---------------------------------------------------------------------------
__global__ __launch_bounds__(256) void convert_wT(
    const float* __restrict__ src, __hip_bfloat16* __restrict__ dst, int K,
    int N, int Kpad, int Npad) {
  int idx = blockIdx.x * 256 + threadIdx.x;
  int per = Kpad * Npad;
  if (idx >= per) return;
  int n = idx / Kpad, k = idx % Kpad;
  float v = (k < K && n < N) ? src[(long)k * N + n] : 0.f;
  dst[idx] = __float2bfloat16(v);
}

// ---------------------------------------------------------------------------
__device__ __forceinline__ float block_sum256(float v, float* sm) {
#pragma unroll
  for (int off = 32; off > 0; off >>= 1) v += __shfl_down(v, off, 64);
  int wid = threadIdx.x >> 6;
  if ((threadIdx.x & 63) == 0) sm[wid] = v;
  __syncthreads();
  float t = sm[0] + sm[1] + sm[2] + sm[3];
  __syncthreads();
  return t;
}

// ---------------------------------------------------------------------------
__global__ __launch_bounds__(256) void rmsnorm_kernel(
    const float* __restrict__ X, const float* __restrict__ w,
    __hip_bfloat16* __restrict__ XN) {
  __shared__ float sm[4];
  const long row = blockIdx.x;
  const float* x = X + row * HDIM;
  float vals[3];
  float s = 0.f;
#pragma unroll
  for (int j = 0; j < 3; ++j) {
    vals[j] = x[threadIdx.x + j * 256];
    s += vals[j] * vals[j];
  }
  float tot = block_sum256(s, sm);
  float scale = rsqrtf(tot / (float)HDIM + 1e-5f);
#pragma unroll
  for (int j = 0; j < 3; ++j) {
    int c = threadIdx.x + j * 256;
    XN[row * HDIM + c] = __float2bfloat16(vals[j] * scale * w[c]);
  }
}

// ---------------------------------------------------------------------------
// Causal depthwise conv (K=4) + SiLU -> bf16 U [BL][512]
// ---------------------------------------------------------------------------
__global__ __launch_bounds__(256) void conv_silu_kernel(
    const float* __restrict__ PROJ, const float* __restrict__ cw,
    const float* __restrict__ cb, __hip_bfloat16* __restrict__ U, int layer) {
  long idx = (long)blockIdx.x * 256 + threadIdx.x;
  if (idx >= (long)BL * 512) return;
  int d = (int)(idx & 511);
  long row = idx >> 9;
  if (d >= DI) {
    U[idx] = __float2bfloat16(0.f);
    return;
  }
  int t = (int)(row & (SEQL - 1));
  const float* w = cw + ((long)layer * DI + d) * KCONV;
  float acc = cb[layer * DI + d];
#pragma unroll
  for (int k = 0; k < KCONV; ++k) {
    int tt = t + k - (KCONV - 1);
    if (tt >= 0) acc += PROJ[(row + k - (KCONV - 1)) * 1000 + d] * w[k];
  }
  U[idx] = __float2bfloat16(acc / (1.f + expf(-acc)));
}

// ---------------------------------------------------------------------------
// SSM[:, :48] fp32 -> bf16 [BL][64]
// ---------------------------------------------------------------------------
__global__ __launch_bounds__(256) void dtconv_kernel(
    const float* __restrict__ SSM, __hip_bfloat16* __restrict__ SSMbf) {
  long idx = (long)blockIdx.x * 256 + threadIdx.x;
  if (idx >= (long)BL * 64) return;
  int c = (int)(idx & 63);
  long row = idx >> 6;
  float v = (c < RRANK) ? SSM[row * 128 + c] : 0.f;
  SSMbf[idx] = __float2bfloat16(v);
}

// ---------------------------------------------------------------------------
// Ubf [8192][512] bf16 -> Ut [8][512][1024] bf16 (tile transpose)
// ---------------------------------------------------------------------------
__global__ __launch_bounds__(256) void transpose_u(
    const unsigned short* __restrict__ Ubf, unsigned short* __restrict__ Ut) {
  __shared__ unsigned short tile[32][33];
  const int d0 = blockIdx.x * 32, t0 = blockIdx.y * 32, b = blockIdx.z;
  const int tx = threadIdx.x & 31, ty = threadIdx.x >> 5;
#pragma unroll
  for (int r = 0; r < 4; ++r) {
    int t = t0 + ty + r * 8;
    tile[ty + r * 8][tx] = Ubf[((size_t)b * 1024 + t) * 512 + d0 + tx];
  }
  __syncthreads();
#pragma unroll
  for (int r = 0; r < 4; ++r) {
    int d = d0 + ty + r * 8;
    Ut[((size_t)b * 512 + d) * 1024 + t0 + tx] = tile[tx][ty + r * 8];
  }
}

// ---------------------------------------------------------------------------
// Yt [8][512][1024] bf16 (valid d<500) -> Ybf [8192][512] with silu(gate)
// ---------------------------------------------------------------------------
__global__ __launch_bounds__(256) void y_gate_kernel(
    const unsigned short* __restrict__ Yt, const float* __restrict__ PROJ,
    unsigned short* __restrict__ Ybf) {
  __shared__ unsigned short tile[32][33];
  const int d0 = blockIdx.x * 32, t0 = blockIdx.y * 32, b = blockIdx.z;
  const int tx = threadIdx.x & 31, ty = threadIdx.x >> 5;
#pragma unroll
  for (int r = 0; r < 4; ++r) {
    int d = d0 + ty + r * 8;
    tile[ty + r * 8][tx] =
        (d < DI) ? Yt[((size_t)b * 512 + d) * 1024 + t0 + tx] : (unsigned short)0;
  }
  __syncthreads();
#pragma unroll
  for (int r = 0; r < 4; ++r) {
    size_t row = (size_t)b * 1024 + t0 + ty + r * 8;
    int d = d0 + tx;
    float yv = 0.f;
    if (d < DI) {
      unsigned int u = ((unsigned int)tile[tx][ty + r * 8]) << 16;
      float y;
      memcpy(&y, &u, 4);
      float g = PROJ[row * 1000 + DI + d];
      yv = y * (g / (1.f + expf(-g)));
    }
    Ybf[row * 512 + d] = (unsigned short)(__hip_bfloat16_raw(__float2bfloat16(yv)).x);
  }
}

// ---------------------------------------------------------------------------
// Chunked parallel SSM scan. Block = one (b,d); tid = chunk*16 + n.
// 16 chunks x 64 steps. dt/u staged in LDS (skewed). Writes Yt[b][d][t] bf16.
// ---------------------------------------------------------------------------
__global__ __launch_bounds__(256) void scan_kernel(
    const float* __restrict__ DTt, const unsigned short* __restrict__ Ut,
    const float* __restrict__ SSM, const float* __restrict__ A_log,
    const float* __restrict__ Dparam, unsigned short* __restrict__ Yt,
    int layer) {
  __shared__ float sdt[1040];
  __shared__ float su[1040];
  __shared__ float s_ap[16][17];
  __shared__ float s_h0[16][17];
  __shared__ float s_hi[16][17];
  const int blk = blockIdx.x;  // 4000
  const int b = blk / DI, d = blk % DI;
  const int tid = threadIdx.x;
  const int c = tid >> 4, n = tid & 15;

  const float* dtp = DTt + ((size_t)b * DI + d) * 1024;
  const unsigned short* up = Ut + ((size_t)b * 512 + d) * 1024;
#pragma unroll
  for (int k = 0; k < 4; ++k) {
    int x = tid + k * 256;
    sdt[x + (x >> 6)] = dtp[x];
    unsigned int uu = ((unsigned int)up[x]) << 16;
    float uf;
    memcpy(&uf, &uu, 4);
    su[x + (x >> 6)] = uf;
  }
  __syncthreads();

  const float An = -expf(A_log[((size_t)layer * DI + d) * NSTATE + n]);
  const float Dp = Dparam[layer * DI + d];
  const int t0 = c * 64;
  const int sb = t0 + c;  // skewed LDS base
  const float* ssmB = SSM + ((size_t)b * 1024 + t0) * 128 + RRANK + n;

  // phase 1: local recurrence from h=0, track product of a
  float h = 0.f, ap = 1.f;
  for (int s = 0; s < 64; ++s) {
    float dt = sdt[sb + s];
    float a = __expf(dt * An);
    h = a * h + dt * su[sb + s] * ssmB[(size_t)s * 128];
    ap *= a;
  }
  s_ap[c][n] = ap;
  s_h0[c][n] = h;
  __syncthreads();

  // phase 2: serial combine over 16 chunks (16 threads)
  if (tid < 16) {
    float hi = 0.f;
    for (int cc = 0; cc < 16; ++cc) {
      s_hi[cc][tid] = hi;
      hi = s_ap[cc][tid] * hi + s_h0[cc][tid];
    }
  }
  __syncthreads();

  // phase 3: re-run with correct h_init, produce y
  h = s_hi[c][n];
  unsigned short* yp = Yt + ((size_t)b * 512 + d) * 1024 + t0;
  for (int s = 0; s < 64; ++s) {
    float dt = sdt[sb + s];
    float u = su[sb + s];
    float a = __expf(dt * An);
    h = a * h + dt * u * ssmB[(size_t)s * 128];
    float p = h * ssmB[(size_t)s * 128 + 16];
    p += __shfl_xor(p, 1, 64);
    p += __shfl_xor(p, 2, 64);
    p += __shfl_xor(p, 4, 64);
    p += __shfl_xor(p, 8, 64);
    if (n == 0) {
      float y = p + u * Dp;
      yp[s] = (unsigned short)(__hip_bfloat16_raw(__float2bfloat16(y)).x);
    }
  }
}

// ---------------------------------------------------------------------------
__global__ __launch_bounds__(256) void final_kernel(
    const float* __restrict__ X, const float* __restrict__ nfw,
    const float* __restrict__ Wcls, float* __restrict__ out) {
  __shared__ float sm[4];
  const int b = blockIdx.x;
  const long row = (long)b * SEQL + (SEQL - 1);
  const float* x = X + row * HDIM;
  float vals[3];
  float s = 0.f;
#pragma unroll
  for (int j = 0; j < 3; ++j) {
    vals[j] = x[threadIdx.x + j * 256];
    s += vals[j] * vals[j];
  }
  float tot = block_sum256(s, sm);
  float scale = rsqrtf(tot / (float)HDIM + 1e-5f);
  float dot = 0.f;
#pragma unroll
  for (int j = 0; j < 3; ++j) {
    int c = threadIdx.x + j * 256;
    dot += vals[j] * scale * nfw[c] * Wcls[c];
  }
  float td = block_sum256(dot, sm);
  if (threadIdx.x == 0) out[b] = td;
}

// ---------------------------------------------------------------------------
extern "C" void kernel_launch(void* const* d_in, const int* in_sizes, int n_in,
                              void* d_out, int out_size, void* d_ws,
                              size_t ws_size, hipStream_t stream) {
  const float* inputs  = (const float*)d_in[0];
  const float* W_down  = (const float*)d_in[1];
  const float* in_proj = (const float*)d_in[2];
  const float* conv_w  = (const float*)d_in[3];
  const float* conv_b  = (const float*)d_in[4];
  const float* x_proj  = (const float*)d_in[5];
  const float* dt_w    = (const float*)d_in[6];
  const float* dt_b    = (const float*)d_in[7];
  const float* A_log   = (const float*)d_in[8];
  const float* D_param = (const float*)d_in[9];
  const float* out_w   = (const float*)d_in[10];
  const float* norm_w  = (const float*)d_in[11];
  const float* norm_fw = (const float*)d_in[12];
  const float* W_cls   = (const float*)d_in[13];
  float* out = (float*)d_out;

  char* ws = (char*)d_ws;
  // --- shared window (0 .. 73400320), init phase holds Abf+Wdbf ---
  __hip_bfloat16* Abf   = (__hip_bfloat16*)(ws + 0);         // 67108864
  __hip_bfloat16* Wdbf  = (__hip_bfloat16*)(ws + 67108864);  // 6291456 -> 73400320
  // layer phase:
  __hip_bfloat16* XNbf  = (__hip_bfloat16*)(ws + 0);         // 12582912
  unsigned short* Yt    = (unsigned short*)(ws + 0);         // 8388608 (aliases XNbf)
  float*          PROJ  = (float*)(ws + 12582912);           // 32768000 -> 45350912
  float*          SSM   = (float*)(ws + 45350912);           // 4194304  -> 49545216
  __hip_bfloat16* SSMbf = (__hip_bfloat16*)(ws + 49545216);  // 1048576  -> 50593792
  __hip_bfloat16* Ubf   = (__hip_bfloat16*)(ws + 50593792);  // 8388608  -> 58982400
  unsigned short* Ut    = (unsigned short*)(ws + 58982400);  // 8388608  -> 67371008
  __hip_bfloat16* Ybf   = (__hip_bfloat16*)(ws + 58982400);  // (aliases Ut)
  // per-layer converted weights (in init-region gap, written after init)
  __hip_bfloat16* inpbf = (__hip_bfloat16*)(ws + 67371008);  // 1572864 -> 68943872
  __hip_bfloat16* xpbf  = (__hip_bfloat16*)(ws + 68943872);  // 131072  -> 69074944
  __hip_bfloat16* dtwbf = (__hip_bfloat16*)(ws + 69074944);  // 65536   -> 69140480
  __hip_bfloat16* outwbf= (__hip_bfloat16*)(ws + 69140480);  // 786432  -> 69926912
  // --- persistent ---
  float*          DTt   = (float*)(ws + 73400320);           // 16384000 -> 89784320
  float*          X     = (float*)(ws + 89784320);           // 25165824 -> 114950144

  // --- init ---
  convert_cast<<<(long)BL * 4096 / 4 / 256, 256, 0, stream>>>(inputs, Abf,
                                                              (long)BL * 4096);
  convert_wT<<<(768 * 4096 + 255) / 256, 256, 0, stream>>>(W_down, Wdbf, 4096,
                                                           768, 4096, 768);
  // X = inputs @ W_down   (8192 x 768 x 4096)
  gemm_mfma<0><<<dim3(768 / 128, BL / 128), 256, 0, stream>>>(
      (const short*)Abf, (const short*)Wdbf, X, nullptr, BL, HDIM, INDIM,
      INDIM, INDIM, HDIM);

  for (int i = 0; i < NLAYER; ++i) {
    // per-layer weight conversion (into init-region gap)
    convert_wT<<<(768 * 1024 + 255) / 256, 256, 0, stream>>>(
        in_proj + (long)i * HDIM * 1000, inpbf, 768, 1000, 768, 1024);
    convert_wT<<<(128 * 512 + 255) / 256, 256, 0, stream>>>(
        x_proj + (long)i * DI * 80, xpbf, 500, 80, 512, 128);
    convert_wT<<<(512 * 64 + 255) / 256, 256, 0, stream>>>(
        dt_w + (long)i * RRANK * DI, dtwbf, 48, 500, 64, 512);
    convert_wT<<<(768 * 512 + 255) / 256, 256, 0, stream>>>(
        out_w + (long)i * DI * HDIM, outwbf, 500, 768, 512, 768);

    rmsnorm_kernel<<<BL, 256, 0, stream>>>(X, norm_w + i * HDIM, XNbf);
    // PROJ = XN @ in_proj[i]   (8192 x 1000 x 768)
    gemm_mfma<0><<<dim3(1024 / 128, BL / 128), 256, 0, stream>>>(
        (const short*)XNbf, (const short*)inpbf, PROJ, nullptr, BL, 1000,
        HDIM, HDIM, HDIM, 1000);
    conv_silu_kernel<<<(long)BL * 512 / 256, 256, 0, stream>>>(
        PROJ, conv_w, conv_b, Ubf, i);
    // SSM = U @ x_proj[i]   (8192 x 80 x 512)
    gemm_mfma<0><<<dim3(1, BL / 128), 256, 0, stream>>>(
        (const short*)Ubf, (const short*)xpbf, SSM, nullptr, BL, 80, 512, 512,
        512, 128);
    dtconv_kernel<<<(long)BL * 64 / 256, 256, 0, stream>>>(SSM, SSMbf);
    // DTt = softplus(SSM[:,:48] @ dt_w[i] + dt_b[i]) stored transposed
    gemm_mfma<3><<<dim3(512 / 128, BL / 128), 256, 0, stream>>>(
        (const short*)SSMbf, (const short*)dtwbf, DTt, dt_b + i * DI, BL, DI,
        64, 64, 64, 0);
    // Ut = transpose(Ubf)
    transpose_u<<<dim3(16, 32, 8), 256, 0, stream>>>((const unsigned short*)Ubf,
                                                     Ut);
    // chunked scan -> Yt
    scan_kernel<<<BATCH * DI, 256, 0, stream>>>(DTt, Ut, SSM, A_log, D_param,
                                                (unsigned short*)(void*)Yt, i);
    // Ybf = transpose(Yt) * silu(gate)
    y_gate_kernel<<<dim3(16, 32, 8), 256, 0, stream>>>(
        (const unsigned short*)(void*)Yt, PROJ, (unsigned short*)Ybf);
    // X += Y @ out_w[i]   (8192 x 768 x 512)
    gemm_mfma<1><<<dim3(768 / 128, BL / 128), 256, 0, stream>>>(
        (const short*)Ybf, (const short*)outwbf, X, nullptr, BL, HDIM, 512,
        512, 512, HDIM);
  }

  final_kernel<<<BATCH, 256, 0, stream>>>(X, norm_fw, W_cls, out);
}

// Round 4
// 1271.728 us; speedup vs baseline: 7.0623x; 1.0859x over previous
//
#include <hip/hip_runtime.h>
#include <hip/hip_bf16.h>

// Problem constants
#define BATCH 8
#define SEQL 1024
#define INDIM 4096
#define HDIM 768
#define DI 500
#define NSTATE 16
#define RRANK 48
#define KCONV 4
#define NLAYER 5
#define BL (BATCH * SEQL)  // 8192

typedef __attribute__((ext_vector_type(8))) short bf16x8;
typedef __attribute__((ext_vector_type(4))) float f32x4;

__device__ __forceinline__ void gl_lds16(const void* g, void* l) {
  __builtin_amdgcn_global_load_lds(
      (const __attribute__((address_space(1))) void*)g,
      (__attribute__((address_space(3))) void*)l, 16, 0, 0);
}

__device__ __forceinline__ unsigned short f2bf(float v) {
  return __hip_bfloat16_raw(__float2bfloat16(v)).x;
}
__device__ __forceinline__ float bf2f(unsigned short h) {
  unsigned int u = ((unsigned int)h) << 16;
  float f;
  memcpy(&f, &u, 4);
  return f;
}

// ---------------------------------------------------------------------------
// bf16 MFMA GEMM: C(M,N) fp32 = A(M,K)bf16 @ Bt(N,K)bf16^T  [+ epilogue]
// 128x128 tile, BK=32, 256 threads = 4 waves (2x2 of 64x64), m97 structure.
// EPI 0: store fp32
// EPI 1: C += (residual accumulate)
// EPI 2: softplus(v+bias[col]) fp32
// EPI 3: softplus(v+bias[col]) stored TRANSPOSED fp32 to C=[b][col][t]
// EPI 4: bf16 split store: col<500 -> D0[row][col]; 500<=col<1000 ->
//        D1[row][col-500]   (in_proj u/gate split)
// ---------------------------------------------------------------------------
template <int EPI>
__global__ __launch_bounds__(256) void gemm_mfma(
    const short* __restrict__ A, const short* __restrict__ Bt,
    float* __restrict__ C, const float* __restrict__ bias,
    unsigned short* __restrict__ D0, unsigned short* __restrict__ D1,
    int M, int N, int K, int lda, int ldb, int ldc) {
  __shared__ short As[128 * 32];
  __shared__ short Bs[128 * 32];
  const int tid = threadIdx.x;
  const int w = tid >> 6, lane = tid & 63;
  const int m0 = blockIdx.y * 128, n0 = blockIdx.x * 128;
  const int wr = w >> 1, wc = w & 1;
  f32x4 acc[4][4] = {};

  const int srow = tid >> 2;
  const int scol = (tid & 3) * 8;
  const short* ga0 = A + (size_t)(m0 + srow) * lda + scol;
  const short* ga1 = A + (size_t)(m0 + 64 + srow) * lda + scol;
  const short* gb0 = Bt + (size_t)(n0 + srow) * ldb + scol;
  const short* gb1 = Bt + (size_t)(n0 + 64 + srow) * ldb + scol;
  short* lA0 = As + w * 512;
  short* lA1 = As + 2048 + w * 512;
  short* lB0 = Bs + w * 512;
  short* lB1 = Bs + 2048 + w * 512;
  const int lr = lane & 15, kb = lane >> 4;

  for (int k0 = 0; k0 < K; k0 += 32) {
    gl_lds16(ga0, lA0);
    gl_lds16(ga1, lA1);
    gl_lds16(gb0, lB0);
    gl_lds16(gb1, lB1);
    ga0 += 32; ga1 += 32; gb0 += 32; gb1 += 32;
    __syncthreads();
    bf16x8 af[4], bfr[4];
#pragma unroll
    for (int i = 0; i < 4; ++i) {
      af[i] = *(const bf16x8*)(As + (wr * 64 + i * 16 + lr) * 32 + kb * 8);
      bfr[i] = *(const bf16x8*)(Bs + (wc * 64 + i * 16 + lr) * 32 + kb * 8);
    }
#pragma unroll
    for (int i = 0; i < 4; ++i)
#pragma unroll
      for (int j = 0; j < 4; ++j)
        acc[i][j] = __builtin_amdgcn_mfma_f32_16x16x32_bf16(af[i], bfr[j],
                                                            acc[i][j], 0, 0, 0);
    __syncthreads();
  }

  // C/D layout (m89): col = lane&15, row = (lane>>4)*4 + reg
#pragma unroll
  for (int i = 0; i < 4; ++i) {
    const int row = m0 + wr * 64 + i * 16 + (lane >> 4) * 4;
#pragma unroll
    for (int j = 0; j < 4; ++j) {
      const int col = n0 + wc * 64 + j * 16 + (lane & 15);
      if (col < N) {
        if (EPI == 3) {
          float4 v4;
#pragma unroll
          for (int r = 0; r < 4; ++r) {
            float v = acc[i][j][r] + bias[col];
            ((float*)&v4)[r] = (v > 15.f) ? v : log1pf(expf(v));
          }
          const int bb = row >> 10, tt = row & 1023;
          *(float4*)&C[((size_t)bb * DI + col) * 1024 + tt] = v4;
        } else if (EPI == 4) {
#pragma unroll
          for (int r = 0; r < 4; ++r) {
            unsigned short h = f2bf(acc[i][j][r]);
            size_t rr = (size_t)(row + r);
            if (col < DI)
              D0[rr * 512 + col] = h;
            else
              D1[rr * 512 + (col - DI)] = h;
          }
        } else {
#pragma unroll
          for (int r = 0; r < 4; ++r) {
            float v = acc[i][j][r];
            size_t idx = (size_t)(row + r) * ldc + col;
            if (EPI == 1) v += C[idx];
            if (EPI == 2) {
              v += bias[col];
              v = (v > 15.f) ? v : log1pf(expf(v));
            }
            C[idx] = v;
          }
        }
      }
    }
  }
}

// ---------------------------------------------------------------------------
// fp32 -> bf16 cast
// ---------------------------------------------------------------------------
__global__ __launch_bounds__(256) void convert_cast(
    const float* __restrict__ src, __hip_bfloat16* __restrict__ dst, long n) {
  long i = ((long)blockIdx.x * 256 + threadIdx.x) * 4;
  if (i >= n) return;
  float4 v = *(const float4*)(src + i);
  dst[i + 0] = __float2bfloat16(v.x);
  dst[i + 1] = __float2bfloat16(v.y);
  dst[i + 2] = __float2bfloat16(v.z);
  dst[i + 3] = __float2bfloat16(v.w);
}

// ---------------------------------------------------------------------------
// Weight convert + transpose + pad: src fp32 [K][N] -> dst bf16 [Npad][Kpad]
// grid.y = layer index
// ---------------------------------------------------------------------------
__global__ __launch_bounds__(256) void convert_wT(
    const float* __restrict__ src, __hip_bfloat16* __restrict__ dst, int K,
    int N, int Kpad, int Npad, long src_lstride, long dst_lstride) {
  int idx = blockIdx.x * 256 + threadIdx.x;
  int per = Kpad * Npad;
  if (idx >= per) return;
  const float* s = src + (long)blockIdx.y * src_lstride;
  __hip_bfloat16* d = dst + (long)blockIdx.y * dst_lstride;
  int n = idx / Kpad, k = idx % Kpad;
  float v = (k < K && n < N) ? s[(long)k * N + n] : 0.f;
  d[idx] = __float2bfloat16(v);
}

// ---------------------------------------------------------------------------
__device__ __forceinline__ float block_sum256(float v, float* sm) {
#pragma unroll
  for (int off = 32; off > 0; off >>= 1) v += __shfl_down(v, off, 64);
  int wid = threadIdx.x >> 6;
  if ((threadIdx.x & 63) == 0) sm[wid] = v;
  __syncthreads();
  float t = sm[0] + sm[1] + sm[2] + sm[3];
  __syncthreads();
  return t;
}

// ---------------------------------------------------------------------------
__global__ __launch_bounds__(256) void rmsnorm_kernel(
    const float* __restrict__ X, const float* __restrict__ w,
    __hip_bfloat16* __restrict__ XN) {
  __shared__ float sm[4];
  const long row = blockIdx.x;
  const float* x = X + row * HDIM;
  float vals[3];
  float s = 0.f;
#pragma unroll
  for (int j = 0; j < 3; ++j) {
    vals[j] = x[threadIdx.x + j * 256];
    s += vals[j] * vals[j];
  }
  float tot = block_sum256(s, sm);
  float scale = rsqrtf(tot / (float)HDIM + 1e-5f);
#pragma unroll
  for (int j = 0; j < 3; ++j) {
    int c = threadIdx.x + j * 256;
    XN[row * HDIM + c] = __float2bfloat16(vals[j] * scale * w[c]);
  }
}

// ---------------------------------------------------------------------------
// Fused: causal depthwise conv(K=4)+SiLU reading Uraw bf16 [8192][512];
// writes Ubf [row][512] AND Ut [8][512][1024] (transposed) from one LDS tile.
// grid = (16 d-tiles, 32 t-tiles, 8 b), 256 threads, 32x32 tiles.
// ---------------------------------------------------------------------------
__global__ __launch_bounds__(256) void conv_fused_kernel(
    const unsigned short* __restrict__ Uraw, const float* __restrict__ cw,
    const float* __restrict__ cb, unsigned short* __restrict__ Ubf,
    unsigned short* __restrict__ Ut, int layer) {
  __shared__ unsigned short tin[35][33];
  __shared__ unsigned short tout[32][33];
  const int d0 = blockIdx.x * 32, t0 = blockIdx.y * 32, b = blockIdx.z;
  const int tx = threadIdx.x & 31, ty = threadIdx.x >> 5;  // ty: 0..7
  // load rows t0-3 .. t0+31 (35 rows)
#pragma unroll
  for (int r = 0; r < 5; ++r) {
    int tr = ty + r * 8;
    if (tr < 35) {
      int t = t0 + tr - (KCONV - 1);
      tin[tr][tx] =
          (t >= 0) ? Uraw[((size_t)b * 1024 + t) * 512 + d0 + tx] : 0;
    }
  }
  __syncthreads();
  const int d = d0 + tx;
  float w0 = 0.f, w1 = 0.f, w2 = 0.f, w3 = 0.f, bias = 0.f;
  if (d < DI) {
    const float* w = cw + ((size_t)layer * DI + d) * KCONV;
    w0 = w[0]; w1 = w[1]; w2 = w[2]; w3 = w[3];
    bias = cb[layer * DI + d];
  }
#pragma unroll
  for (int r = 0; r < 4; ++r) {
    const int tt = ty + r * 8;  // 0..31
    unsigned short h = 0;
    if (d < DI) {
      float a = bias + w0 * bf2f(tin[tt][tx]) + w1 * bf2f(tin[tt + 1][tx]) +
                w2 * bf2f(tin[tt + 2][tx]) + w3 * bf2f(tin[tt + 3][tx]);
      h = f2bf(a / (1.f + expf(-a)));
    }
    tout[tt][tx] = h;
    Ubf[((size_t)b * 1024 + t0 + tt) * 512 + d] = h;
  }
  __syncthreads();
#pragma unroll
  for (int r = 0; r < 4; ++r) {
    const int dd = ty + r * 8;
    Ut[((size_t)b * 512 + d0 + dd) * 1024 + t0 + tx] = tout[tx][dd];
  }
}

// ---------------------------------------------------------------------------
// SSM[:, :48] fp32 -> bf16 [BL][64]
// ---------------------------------------------------------------------------
__global__ __launch_bounds__(256) void dtconv_kernel(
    const float* __restrict__ SSM, __hip_bfloat16* __restrict__ SSMbf) {
  long idx = (long)blockIdx.x * 256 + threadIdx.x;
  if (idx >= (long)BL * 64) return;
  int c = (int)(idx & 63);
  long row = idx >> 6;
  float v = (c < RRANK) ? SSM[row * 128 + c] : 0.f;
  SSMbf[idx] = __float2bfloat16(v);
}

// ---------------------------------------------------------------------------
// Yt [8][512][1024] bf16 -> Ybf [8192][512] with silu(gate), gate bf16
// ---------------------------------------------------------------------------
__global__ __launch_bounds__(256) void y_gate_kernel(
    const unsigned short* __restrict__ Yt, const unsigned short* __restrict__ G,
    unsigned short* __restrict__ Ybf) {
  __shared__ unsigned short tile[32][33];
  const int d0 = blockIdx.x * 32, t0 = blockIdx.y * 32, b = blockIdx.z;
  const int tx = threadIdx.x & 31, ty = threadIdx.x >> 5;
#pragma unroll
  for (int r = 0; r < 4; ++r) {
    int d = d0 + ty + r * 8;
    tile[ty + r * 8][tx] =
        (d < DI) ? Yt[((size_t)b * 512 + d) * 1024 + t0 + tx]
                 : (unsigned short)0;
  }
  __syncthreads();
#pragma unroll
  for (int r = 0; r < 4; ++r) {
    size_t row = (size_t)b * 1024 + t0 + ty + r * 8;
    int d = d0 + tx;
    float yv = 0.f;
    if (d < DI) {
      float y = bf2f(tile[tx][ty + r * 8]);
      float g = bf2f(G[row * 512 + d]);
      yv = y * (g / (1.f + expf(-g)));
    }
    Ybf[row * 512 + d] = f2bf(yv);
  }
}

// ---------------------------------------------------------------------------
// Chunked parallel SSM scan. Block = one (b,d); tid = chunk*16 + n.
// 16 chunks x 64 steps. dt/u staged in LDS (skewed). Writes Yt[b][d][t] bf16.
// ---------------------------------------------------------------------------
__global__ __launch_bounds__(256) void scan_kernel(
    const float* __restrict__ DTt, const unsigned short* __restrict__ Ut,
    const float* __restrict__ SSM, const float* __restrict__ A_log,
    const float* __restrict__ Dparam, unsigned short* __restrict__ Yt,
    int layer) {
  __shared__ float sdt[1040];
  __shared__ float su[1040];
  __shared__ float s_ap[16][17];
  __shared__ float s_h0[16][17];
  __shared__ float s_hi[16][17];
  const int blk = blockIdx.x;  // 4000
  const int b = blk / DI, d = blk % DI;
  const int tid = threadIdx.x;
  const int c = tid >> 4, n = tid & 15;

  const float* dtp = DTt + ((size_t)b * DI + d) * 1024;
  const unsigned short* up = Ut + ((size_t)b * 512 + d) * 1024;
#pragma unroll
  for (int k = 0; k < 4; ++k) {
    int x = tid + k * 256;
    sdt[x + (x >> 6)] = dtp[x];
    su[x + (x >> 6)] = bf2f(up[x]);
  }
  __syncthreads();

  const float An = -expf(A_log[((size_t)layer * DI + d) * NSTATE + n]);
  const float Dp = Dparam[layer * DI + d];
  const int t0 = c * 64;
  const int sb = t0 + c;  // skewed LDS base
  const float* ssmB = SSM + ((size_t)b * 1024 + t0) * 128 + RRANK + n;

  // phase 1: local recurrence from h=0, track product of a
  float h = 0.f, ap = 1.f;
  for (int s = 0; s < 64; ++s) {
    float dt = sdt[sb + s];
    float a = __expf(dt * An);
    h = a * h + dt * su[sb + s] * ssmB[(size_t)s * 128];
    ap *= a;
  }
  s_ap[c][n] = ap;
  s_h0[c][n] = h;
  __syncthreads();

  // phase 2: serial combine over 16 chunks (16 threads)
  if (tid < 16) {
    float hi = 0.f;
    for (int cc = 0; cc < 16; ++cc) {
      s_hi[cc][tid] = hi;
      hi = s_ap[cc][tid] * hi + s_h0[cc][tid];
    }
  }
  __syncthreads();

  // phase 3: re-run with correct h_init, produce y
  h = s_hi[c][n];
  unsigned short* yp = Yt + ((size_t)b * 512 + d) * 1024 + t0;
  for (int s = 0; s < 64; ++s) {
    float dt = sdt[sb + s];
    float u = su[sb + s];
    float a = __expf(dt * An);
    h = a * h + dt * u * ssmB[(size_t)s * 128];
    float p = h * ssmB[(size_t)s * 128 + 16];
    p += __shfl_xor(p, 1, 64);
    p += __shfl_xor(p, 2, 64);
    p += __shfl_xor(p, 4, 64);
    p += __shfl_xor(p, 8, 64);
    if (n == 0) {
      float y = p + u * Dp;
      yp[s] = f2bf(y);
    }
  }
}

// ---------------------------------------------------------------------------
__global__ __launch_bounds__(256) void final_kernel(
    const float* __restrict__ X, const float* __restrict__ nfw,
    const float* __restrict__ Wcls, float* __restrict__ out) {
  __shared__ float sm[4];
  const int b = blockIdx.x;
  const long row = (long)b * SEQL + (SEQL - 1);
  const float* x = X + row * HDIM;
  float vals[3];
  float s = 0.f;
#pragma unroll
  for (int j = 0; j < 3; ++j) {
    vals[j] = x[threadIdx.x + j * 256];
    s += vals[j] * vals[j];
  }
  float tot = block_sum256(s, sm);
  float scale = rsqrtf(tot / (float)HDIM + 1e-5f);
  float dot = 0.f;
#pragma unroll
  for (int j = 0; j < 3; ++j) {
    int c = threadIdx.x + j * 256;
    dot += vals[j] * scale * nfw[c] * Wcls[c];
  }
  float td = block_sum256(dot, sm);
  if (threadIdx.x == 0) out[b] = td;
}

// ---------------------------------------------------------------------------
extern "C" void kernel_launch(void* const* d_in, const int* in_sizes, int n_in,
                              void* d_out, int out_size, void* d_ws,
                              size_t ws_size, hipStream_t stream) {
  const float* inputs  = (const float*)d_in[0];
  const float* W_down  = (const float*)d_in[1];
  const float* in_proj = (const float*)d_in[2];
  const float* conv_w  = (const float*)d_in[3];
  const float* conv_b  = (const float*)d_in[4];
  const float* x_proj  = (const float*)d_in[5];
  const float* dt_w    = (const float*)d_in[6];
  const float* dt_b    = (const float*)d_in[7];
  const float* A_log   = (const float*)d_in[8];
  const float* D_param = (const float*)d_in[9];
  const float* out_w   = (const float*)d_in[10];
  const float* norm_w  = (const float*)d_in[11];
  const float* norm_fw = (const float*)d_in[12];
  const float* W_cls   = (const float*)d_in[13];
  float* out = (float*)d_out;

  char* ws = (char*)d_ws;
  // --- init phase (0 .. 73,400,320): Abf + Wdbf ---
  __hip_bfloat16* Abf   = (__hip_bfloat16*)(ws + 0);         // 67108864
  __hip_bfloat16* Wdbf  = (__hip_bfloat16*)(ws + 67108864);  // -> 73400320
  // --- layer phase (aliases init region) ---
  __hip_bfloat16* XNbf  = (__hip_bfloat16*)(ws + 0);         // 12582912
  unsigned short* Yt    = (unsigned short*)(ws + 0);         // 8388608 (alias)
  float*          DTt   = (float*)(ws + 12582912);           // 16384000 -> 28966912
  unsigned short* Uraw  = (unsigned short*)(ws + 28966912);  // 8388608 -> 37355520
  unsigned short* Ybf   = (unsigned short*)(ws + 28966912);  // (alias, after Uraw dead)
  unsigned short* Gate  = (unsigned short*)(ws + 37355520);  // 8388608 -> 45744128
  unsigned short* Ubf   = (unsigned short*)(ws + 45744128);  // 8388608 -> 54132736
  unsigned short* Ut    = (unsigned short*)(ws + 54132736);  // 8388608 -> 62521344
  float*          SSM   = (float*)(ws + 62521344);           // 4194304 -> 66715648
  __hip_bfloat16* SSMbf = (__hip_bfloat16*)(ws + 66715648);  // 1048576 -> 67764224
  // --- persistent ---
  float*          X     = (float*)(ws + 73400320);           // 25165824 -> 98566144
  __hip_bfloat16* inpbf = (__hip_bfloat16*)(ws + 98566144);  // 7864320 -> 106430464
  __hip_bfloat16* xpbf  = (__hip_bfloat16*)(ws + 106430464); // 655360  -> 107085824
  __hip_bfloat16* dtwbf = (__hip_bfloat16*)(ws + 107085824); // 327680  -> 107413504
  __hip_bfloat16* outwbf= (__hip_bfloat16*)(ws + 107413504); // 3932160 -> 111345664

  // --- init: conversions (all layers) ---
  convert_cast<<<(long)BL * 4096 / 4 / 256, 256, 0, stream>>>(inputs, Abf,
                                                              (long)BL * 4096);
  convert_wT<<<dim3((768 * 4096 + 255) / 256, 1), 256, 0, stream>>>(
      W_down, Wdbf, 4096, 768, 4096, 768, 0, 0);
  convert_wT<<<dim3((768 * 1024 + 255) / 256, NLAYER), 256, 0, stream>>>(
      in_proj, inpbf, 768, 1000, 768, 1024, (long)HDIM * 1000, 768 * 1024);
  convert_wT<<<dim3((128 * 512 + 255) / 256, NLAYER), 256, 0, stream>>>(
      x_proj, xpbf, 500, 80, 512, 128, (long)DI * 80, 128 * 512);
  convert_wT<<<dim3((512 * 64 + 255) / 256, NLAYER), 256, 0, stream>>>(
      dt_w, dtwbf, 48, 500, 64, 512, (long)RRANK * DI, 512 * 64);
  convert_wT<<<dim3((768 * 512 + 255) / 256, NLAYER), 256, 0, stream>>>(
      out_w, outwbf, 500, 768, 512, 768, (long)DI * HDIM, 768 * 512);

  // X = inputs @ W_down   (8192 x 768 x 4096)
  gemm_mfma<0><<<dim3(768 / 128, BL / 128), 256, 0, stream>>>(
      (const short*)Abf, (const short*)Wdbf, X, nullptr, nullptr, nullptr, BL,
      HDIM, INDIM, INDIM, INDIM, HDIM);

  for (int i = 0; i < NLAYER; ++i) {
    rmsnorm_kernel<<<BL, 256, 0, stream>>>(X, norm_w + i * HDIM, XNbf);
    // Uraw/Gate = split(XN @ in_proj[i]) bf16  (8192 x 1000 x 768)
    gemm_mfma<4><<<dim3(1024 / 128, BL / 128), 256, 0, stream>>>(
        (const short*)XNbf, (const short*)(inpbf + (long)i * 768 * 1024),
        nullptr, nullptr, Uraw, Gate, BL, 1000, HDIM, HDIM, HDIM, 0);
    // conv+silu -> Ubf (row-major) + Ut (transposed)
    conv_fused_kernel<<<dim3(16, 32, 8), 256, 0, stream>>>(Uraw, conv_w,
                                                           conv_b, Ubf, Ut, i);
    // SSM = U @ x_proj[i]   (8192 x 80 x 512)
    gemm_mfma<0><<<dim3(1, BL / 128), 256, 0, stream>>>(
        (const short*)Ubf, (const short*)(xpbf + (long)i * 128 * 512), SSM,
        nullptr, nullptr, nullptr, BL, 80, 512, 512, 512, 128);
    dtconv_kernel<<<(long)BL * 64 / 256, 256, 0, stream>>>(SSM, SSMbf);
    // DTt = softplus(SSM[:,:48] @ dt_w[i] + dt_b[i]) stored transposed
    gemm_mfma<3><<<dim3(512 / 128, BL / 128), 256, 0, stream>>>(
        (const short*)SSMbf, (const short*)(dtwbf + (long)i * 512 * 64), DTt,
        dt_b + i * DI, nullptr, nullptr, BL, DI, 64, 64, 64, 0);
    // chunked scan -> Yt
    scan_kernel<<<BATCH * DI, 256, 0, stream>>>(DTt, Ut, SSM, A_log, D_param,
                                                Yt, i);
    // Ybf = transpose(Yt) * silu(gate)
    y_gate_kernel<<<dim3(16, 32, 8), 256, 0, stream>>>(Yt, Gate, Ybf);
    // X += Y @ out_w[i]   (8192 x 768 x 512)
    gemm_mfma<1><<<dim3(768 / 128, BL / 128), 256, 0, stream>>>(
        (const short*)Ybf, (const short*)(outwbf + (long)i * 768 * 512), X,
        nullptr, nullptr, nullptr, BL, HDIM, 512, 512, 512, HDIM);
  }

  final_kernel<<<BATCH, 256, 0, stream>>>(X, norm_fw, W_cls, out);
}

// Round 5
// 1265.025 us; speedup vs baseline: 7.0997x; 1.0053x over previous
//
#include <hip/hip_runtime.h>
#include <hip/hip_bf16.h>

// Problem constants
#define BATCH 8
#define SEQL 1024
#define INDIM 4096
#define HDIM 768
#define DI 500
#define NSTATE 16
#define RRANK 48
#define KCONV 4
#define NLAYER 5
#define BL (BATCH * SEQL)  // 8192

typedef __attribute__((ext_vector_type(8))) short bf16x8;
typedef __attribute__((ext_vector_type(4))) float f32x4;

__device__ __forceinline__ void gl_lds16(const void* g, void* l) {
  __builtin_amdgcn_global_load_lds(
      (const __attribute__((address_space(1))) void*)g,
      (__attribute__((address_space(3))) void*)l, 16, 0, 0);
}

__device__ __forceinline__ unsigned short f2bf(float v) {
  return __hip_bfloat16_raw(__float2bfloat16(v)).x;
}
__device__ __forceinline__ float bf2f(unsigned short h) {
  unsigned int u = ((unsigned int)h) << 16;
  float f;
  memcpy(&f, &u, 4);
  return f;
}

// ---------------------------------------------------------------------------
// bf16 MFMA GEMM: C(M,N) fp32 = A(M,K)bf16 @ Bt(N,K)bf16^T  [+ epilogue]
// 128x128 tile, BK=32, 256 threads = 4 waves (2x2 of 64x64).
// Double-buffered LDS (prefetch next K-tile during compute), chunk-XOR
// swizzle (both-sides with global_load_lds: pre-swizzled global source +
// XOR'd ds_read) kills the 8-way bank conflict of the 64B LDS row.
// EPI 0: store fp32
// EPI 1: C += (residual accumulate)
// EPI 3: softplus(v+bias[col]) stored TRANSPOSED fp32 to C=[b][col][t]
// EPI 4: bf16 split store: col<500 -> D0[row][col]; else D1[row][col-500]
// EPI 5: fp32 store (col<N) + bf16 D0[row][64] = (col<48 ? v : 0)
// ---------------------------------------------------------------------------
template <int EPI>
__global__ __launch_bounds__(256) void gemm_mfma(
    const short* __restrict__ A, const short* __restrict__ Bt,
    float* __restrict__ C, const float* __restrict__ bias,
    unsigned short* __restrict__ D0, unsigned short* __restrict__ D1,
    int M, int N, int K, int lda, int ldb, int ldc) {
  __shared__ short As[2][128 * 32];
  __shared__ short Bs[2][128 * 32];
  const int tid = threadIdx.x;
  const int w = tid >> 6, lane = tid & 63;
  const int m0 = blockIdx.y * 128, n0 = blockIdx.x * 128;
  const int wr = w >> 1, wc = w & 1;
  f32x4 acc[4][4] = {};

  const int srow = tid >> 2;  // tile row 0..63 (each half)
  const int cpos = tid & 3;   // 16B chunk slot in LDS
  // pre-swizzle: this LDS slot receives data[row][cpos ^ ((row>>1)&3)]
  // ((row+64)>>1)&3 == (row>>1)&3, so one offset serves both halves.
  const int sc = (cpos ^ ((srow >> 1) & 3)) * 8;
  const short* ga0 = A + (size_t)(m0 + srow) * lda + sc;
  const short* ga1 = A + (size_t)(m0 + 64 + srow) * lda + sc;
  const short* gb0 = Bt + (size_t)(n0 + srow) * ldb + sc;
  const short* gb1 = Bt + (size_t)(n0 + 64 + srow) * ldb + sc;
  const int lr = lane & 15, kb = lane >> 4;
  const int kbx = (kb ^ ((lr >> 1) & 3)) * 8;  // reader-side XOR'd chunk

  auto stage = [&](int buf, int k0) {
    gl_lds16(ga0 + k0, &As[buf][w * 512]);
    gl_lds16(ga1 + k0, &As[buf][2048 + w * 512]);
    gl_lds16(gb0 + k0, &Bs[buf][w * 512]);
    gl_lds16(gb1 + k0, &Bs[buf][2048 + w * 512]);
  };
  auto compute = [&](int buf) {
    bf16x8 af[4], bfr[4];
#pragma unroll
    for (int i = 0; i < 4; ++i) {
      af[i] = *(const bf16x8*)&As[buf][(wr * 64 + i * 16 + lr) * 32 + kbx];
      bfr[i] = *(const bf16x8*)&Bs[buf][(wc * 64 + i * 16 + lr) * 32 + kbx];
    }
#pragma unroll
    for (int i = 0; i < 4; ++i)
#pragma unroll
      for (int j = 0; j < 4; ++j)
        acc[i][j] = __builtin_amdgcn_mfma_f32_16x16x32_bf16(af[i], bfr[j],
                                                            acc[i][j], 0, 0, 0);
  };

  const int nk = K >> 5;
  stage(0, 0);
  __syncthreads();  // compiler drains vmcnt(0) before barrier
  int cur = 0;
  for (int t = 0; t < nk - 1; ++t) {
    stage(cur ^ 1, (t + 1) * 32);  // prefetch next tile (in flight...)
    compute(cur);                  // ...during ds_read + MFMA
    __syncthreads();               // drains vmcnt+lgkm, one barrier/iter
    cur ^= 1;
  }
  compute(cur);

  // C/D layout (m89): col = lane&15, row = (lane>>4)*4 + reg
#pragma unroll
  for (int i = 0; i < 4; ++i) {
    const int row = m0 + wr * 64 + i * 16 + (lane >> 4) * 4;
#pragma unroll
    for (int j = 0; j < 4; ++j) {
      const int col = n0 + wc * 64 + j * 16 + (lane & 15);
      if (EPI == 3) {
        if (col < N) {
          float4 v4;
#pragma unroll
          for (int r = 0; r < 4; ++r) {
            float v = acc[i][j][r] + bias[col];
            ((float*)&v4)[r] = (v > 15.f) ? v : log1pf(expf(v));
          }
          const int bb = row >> 10, tt = row & 1023;
          *(float4*)&C[((size_t)bb * DI + col) * 1024 + tt] = v4;
        }
      } else if (EPI == 4) {
#pragma unroll
        for (int r = 0; r < 4; ++r) {
          unsigned short h = f2bf(acc[i][j][r]);
          size_t rr = (size_t)(row + r);
          if (col < DI)
            D0[rr * 512 + col] = h;
          else
            D1[rr * 512 + (col - DI)] = h;
        }
      } else if (EPI == 5) {
#pragma unroll
        for (int r = 0; r < 4; ++r) {
          float v = acc[i][j][r];
          size_t rr = (size_t)(row + r);
          if (col < N) C[rr * ldc + col] = v;
          if (col < 64) D0[rr * 64 + col] = f2bf(col < RRANK ? v : 0.f);
        }
      } else {
        if (col < N) {
#pragma unroll
          for (int r = 0; r < 4; ++r) {
            float v = acc[i][j][r];
            size_t idx = (size_t)(row + r) * ldc + col;
            if (EPI == 1) v += C[idx];
            C[idx] = v;
          }
        }
      }
    }
  }
}

// ---------------------------------------------------------------------------
// fp32 -> bf16 cast
// ---------------------------------------------------------------------------
__global__ __launch_bounds__(256) void convert_cast(
    const float* __restrict__ src, __hip_bfloat16* __restrict__ dst, long n) {
  long i = ((long)blockIdx.x * 256 + threadIdx.x) * 4;
  if (i >= n) return;
  float4 v = *(const float4*)(src + i);
  dst[i + 0] = __float2bfloat16(v.x);
  dst[i + 1] = __float2bfloat16(v.y);
  dst[i + 2] = __float2bfloat16(v.z);
  dst[i + 3] = __float2bfloat16(v.w);
}

// ---------------------------------------------------------------------------
// Weight convert + transpose + pad: src fp32 [K][N] -> dst bf16 [Npad][Kpad]
// grid.y = layer index
// ---------------------------------------------------------------------------
__global__ __launch_bounds__(256) void convert_wT(
    const float* __restrict__ src, __hip_bfloat16* __restrict__ dst, int K,
    int N, int Kpad, int Npad, long src_lstride, long dst_lstride) {
  int idx = blockIdx.x * 256 + threadIdx.x;
  int per = Kpad * Npad;
  if (idx >= per) return;
  const float* s = src + (long)blockIdx.y * src_lstride;
  __hip_bfloat16* d = dst + (long)blockIdx.y * dst_lstride;
  int n = idx / Kpad, k = idx % Kpad;
  float v = (k < K && n < N) ? s[(long)k * N + n] : 0.f;
  d[idx] = __float2bfloat16(v);
}

// ---------------------------------------------------------------------------
__device__ __forceinline__ float block_sum256(float v, float* sm) {
#pragma unroll
  for (int off = 32; off > 0; off >>= 1) v += __shfl_down(v, off, 64);
  int wid = threadIdx.x >> 6;
  if ((threadIdx.x & 63) == 0) sm[wid] = v;
  __syncthreads();
  float t = sm[0] + sm[1] + sm[2] + sm[3];
  __syncthreads();
  return t;
}

// ---------------------------------------------------------------------------
__global__ __launch_bounds__(256) void rmsnorm_kernel(
    const float* __restrict__ X, const float* __restrict__ w,
    __hip_bfloat16* __restrict__ XN) {
  __shared__ float sm[4];
  const long row = blockIdx.x;
  const float* x = X + row * HDIM;
  float vals[3];
  float s = 0.f;
#pragma unroll
  for (int j = 0; j < 3; ++j) {
    vals[j] = x[threadIdx.x + j * 256];
    s += vals[j] * vals[j];
  }
  float tot = block_sum256(s, sm);
  float scale = rsqrtf(tot / (float)HDIM + 1e-5f);
#pragma unroll
  for (int j = 0; j < 3; ++j) {
    int c = threadIdx.x + j * 256;
    XN[row * HDIM + c] = __float2bfloat16(vals[j] * scale * w[c]);
  }
}

// ---------------------------------------------------------------------------
// Fused: causal depthwise conv(K=4)+SiLU reading Uraw bf16 [8192][512];
// writes Ubf [row][512] AND Ut [8][512][1024] (transposed) from one LDS tile.
// ---------------------------------------------------------------------------
__global__ __launch_bounds__(256) void conv_fused_kernel(
    const unsigned short* __restrict__ Uraw, const float* __restrict__ cw,
    const float* __restrict__ cb, unsigned short* __restrict__ Ubf,
    unsigned short* __restrict__ Ut, int layer) {
  __shared__ unsigned short tin[35][33];
  __shared__ unsigned short tout[32][33];
  const int d0 = blockIdx.x * 32, t0 = blockIdx.y * 32, b = blockIdx.z;
  const int tx = threadIdx.x & 31, ty = threadIdx.x >> 5;  // ty: 0..7
#pragma unroll
  for (int r = 0; r < 5; ++r) {
    int tr = ty + r * 8;
    if (tr < 35) {
      int t = t0 + tr - (KCONV - 1);
      tin[tr][tx] =
          (t >= 0) ? Uraw[((size_t)b * 1024 + t) * 512 + d0 + tx] : 0;
    }
  }
  __syncthreads();
  const int d = d0 + tx;
  float w0 = 0.f, w1 = 0.f, w2 = 0.f, w3 = 0.f, bias = 0.f;
  if (d < DI) {
    const float* w = cw + ((size_t)layer * DI + d) * KCONV;
    w0 = w[0]; w1 = w[1]; w2 = w[2]; w3 = w[3];
    bias = cb[layer * DI + d];
  }
#pragma unroll
  for (int r = 0; r < 4; ++r) {
    const int tt = ty + r * 8;
    unsigned short h = 0;
    if (d < DI) {
      float a = bias + w0 * bf2f(tin[tt][tx]) + w1 * bf2f(tin[tt + 1][tx]) +
                w2 * bf2f(tin[tt + 2][tx]) + w3 * bf2f(tin[tt + 3][tx]);
      h = f2bf(a / (1.f + expf(-a)));
    }
    tout[tt][tx] = h;
    Ubf[((size_t)b * 1024 + t0 + tt) * 512 + d] = h;
  }
  __syncthreads();
#pragma unroll
  for (int r = 0; r < 4; ++r) {
    const int dd = ty + r * 8;
    Ut[((size_t)b * 512 + d0 + dd) * 1024 + t0 + tx] = tout[tx][dd];
  }
}

// ---------------------------------------------------------------------------
// Yt [8][512][1024] bf16 -> Ybf [8192][512] with silu(gate), gate bf16
// ---------------------------------------------------------------------------
__global__ __launch_bounds__(256) void y_gate_kernel(
    const unsigned short* __restrict__ Yt, const unsigned short* __restrict__ G,
    unsigned short* __restrict__ Ybf) {
  __shared__ unsigned short tile[32][33];
  const int d0 = blockIdx.x * 32, t0 = blockIdx.y * 32, b = blockIdx.z;
  const int tx = threadIdx.x & 31, ty = threadIdx.x >> 5;
#pragma unroll
  for (int r = 0; r < 4; ++r) {
    int d = d0 + ty + r * 8;
    tile[ty + r * 8][tx] =
        (d < DI) ? Yt[((size_t)b * 512 + d) * 1024 + t0 + tx]
                 : (unsigned short)0;
  }
  __syncthreads();
#pragma unroll
  for (int r = 0; r < 4; ++r) {
    size_t row = (size_t)b * 1024 + t0 + ty + r * 8;
    int d = d0 + tx;
    float yv = 0.f;
    if (d < DI) {
      float y = bf2f(tile[tx][ty + r * 8]);
      float g = bf2f(G[row * 512 + d]);
      yv = y * (g / (1.f + expf(-g)));
    }
    Ybf[row * 512 + d] = f2bf(yv);
  }
}

// ---------------------------------------------------------------------------
// Chunked parallel SSM scan. Block = one (b,d); tid = chunk*16 + n.
// ---------------------------------------------------------------------------
__global__ __launch_bounds__(256) void scan_kernel(
    const float* __restrict__ DTt, const unsigned short* __restrict__ Ut,
    const float* __restrict__ SSM, const float* __restrict__ A_log,
    const float* __restrict__ Dparam, unsigned short* __restrict__ Yt,
    int layer) {
  __shared__ float sdt[1040];
  __shared__ float su[1040];
  __shared__ float s_ap[16][17];
  __shared__ float s_h0[16][17];
  __shared__ float s_hi[16][17];
  const int blk = blockIdx.x;
  const int b = blk / DI, d = blk % DI;
  const int tid = threadIdx.x;
  const int c = tid >> 4, n = tid & 15;

  const float* dtp = DTt + ((size_t)b * DI + d) * 1024;
  const unsigned short* up = Ut + ((size_t)b * 512 + d) * 1024;
#pragma unroll
  for (int k = 0; k < 4; ++k) {
    int x = tid + k * 256;
    sdt[x + (x >> 6)] = dtp[x];
    su[x + (x >> 6)] = bf2f(up[x]);
  }
  __syncthreads();

  const float An = -expf(A_log[((size_t)layer * DI + d) * NSTATE + n]);
  const float Dp = Dparam[layer * DI + d];
  const int t0 = c * 64;
  const int sb = t0 + c;
  const float* ssmB = SSM + ((size_t)b * 1024 + t0) * 128 + RRANK + n;

  float h = 0.f, ap = 1.f;
  for (int s = 0; s < 64; ++s) {
    float dt = sdt[sb + s];
    float a = __expf(dt * An);
    h = a * h + dt * su[sb + s] * ssmB[(size_t)s * 128];
    ap *= a;
  }
  s_ap[c][n] = ap;
  s_h0[c][n] = h;
  __syncthreads();

  if (tid < 16) {
    float hi = 0.f;
    for (int cc = 0; cc < 16; ++cc) {
      s_hi[cc][tid] = hi;
      hi = s_ap[cc][tid] * hi + s_h0[cc][tid];
    }
  }
  __syncthreads();

  h = s_hi[c][n];
  unsigned short* yp = Yt + ((size_t)b * 512 + d) * 1024 + t0;
  for (int s = 0; s < 64; ++s) {
    float dt = sdt[sb + s];
    float u = su[sb + s];
    float a = __expf(dt * An);
    h = a * h + dt * u * ssmB[(size_t)s * 128];
    float p = h * ssmB[(size_t)s * 128 + 16];
    p += __shfl_xor(p, 1, 64);
    p += __shfl_xor(p, 2, 64);
    p += __shfl_xor(p, 4, 64);
    p += __shfl_xor(p, 8, 64);
    if (n == 0) {
      float y = p + u * Dp;
      yp[s] = f2bf(y);
    }
  }
}

// ---------------------------------------------------------------------------
__global__ __launch_bounds__(256) void final_kernel(
    const float* __restrict__ X, const float* __restrict__ nfw,
    const float* __restrict__ Wcls, float* __restrict__ out) {
  __shared__ float sm[4];
  const int b = blockIdx.x;
  const long row = (long)b * SEQL + (SEQL - 1);
  const float* x = X + row * HDIM;
  float vals[3];
  float s = 0.f;
#pragma unroll
  for (int j = 0; j < 3; ++j) {
    vals[j] = x[threadIdx.x + j * 256];
    s += vals[j] * vals[j];
  }
  float tot = block_sum256(s, sm);
  float scale = rsqrtf(tot / (float)HDIM + 1e-5f);
  float dot = 0.f;
#pragma unroll
  for (int j = 0; j < 3; ++j) {
    int c = threadIdx.x + j * 256;
    dot += vals[j] * scale * nfw[c] * Wcls[c];
  }
  float td = block_sum256(dot, sm);
  if (threadIdx.x == 0) out[b] = td;
}

// ---------------------------------------------------------------------------
extern "C" void kernel_launch(void* const* d_in, const int* in_sizes, int n_in,
                              void* d_out, int out_size, void* d_ws,
                              size_t ws_size, hipStream_t stream) {
  const float* inputs  = (const float*)d_in[0];
  const float* W_down  = (const float*)d_in[1];
  const float* in_proj = (const float*)d_in[2];
  const float* conv_w  = (const float*)d_in[3];
  const float* conv_b  = (const float*)d_in[4];
  const float* x_proj  = (const float*)d_in[5];
  const float* dt_w    = (const float*)d_in[6];
  const float* dt_b    = (const float*)d_in[7];
  const float* A_log   = (const float*)d_in[8];
  const float* D_param = (const float*)d_in[9];
  const float* out_w   = (const float*)d_in[10];
  const float* norm_w  = (const float*)d_in[11];
  const float* norm_fw = (const float*)d_in[12];
  const float* W_cls   = (const float*)d_in[13];
  float* out = (float*)d_out;

  char* ws = (char*)d_ws;
  // --- init phase (0 .. 73,400,320): Abf + Wdbf ---
  __hip_bfloat16* Abf   = (__hip_bfloat16*)(ws + 0);         // 67108864
  __hip_bfloat16* Wdbf  = (__hip_bfloat16*)(ws + 67108864);  // -> 73400320
  // --- layer phase (aliases init region) ---
  __hip_bfloat16* XNbf  = (__hip_bfloat16*)(ws + 0);         // 12582912
  unsigned short* Yt    = (unsigned short*)(ws + 0);         // 8388608 (alias)
  float*          DTt   = (float*)(ws + 12582912);           // 16384000 -> 28966912
  unsigned short* Uraw  = (unsigned short*)(ws + 28966912);  // 8388608 -> 37355520
  unsigned short* Ybf   = (unsigned short*)(ws + 28966912);  // (alias, Uraw dead)
  unsigned short* Gate  = (unsigned short*)(ws + 37355520);  // 8388608 -> 45744128
  unsigned short* Ubf   = (unsigned short*)(ws + 45744128);  // 8388608 -> 54132736
  unsigned short* Ut    = (unsigned short*)(ws + 54132736);  // 8388608 -> 62521344
  float*          SSM   = (float*)(ws + 62521344);           // 4194304 -> 66715648
  __hip_bfloat16* SSMbf = (__hip_bfloat16*)(ws + 66715648);  // 1048576 -> 67764224
  // --- persistent ---
  float*          X     = (float*)(ws + 73400320);           // 25165824 -> 98566144
  __hip_bfloat16* inpbf = (__hip_bfloat16*)(ws + 98566144);  // 7864320 -> 106430464
  __hip_bfloat16* xpbf  = (__hip_bfloat16*)(ws + 106430464); // 655360  -> 107085824
  __hip_bfloat16* dtwbf = (__hip_bfloat16*)(ws + 107085824); // 327680  -> 107413504
  __hip_bfloat16* outwbf= (__hip_bfloat16*)(ws + 107413504); // 3932160 -> 111345664

  // --- init: conversions (all layers) ---
  convert_cast<<<(long)BL * 4096 / 4 / 256, 256, 0, stream>>>(inputs, Abf,
                                                              (long)BL * 4096);
  convert_wT<<<dim3((768 * 4096 + 255) / 256, 1), 256, 0, stream>>>(
      W_down, Wdbf, 4096, 768, 4096, 768, 0, 0);
  convert_wT<<<dim3((768 * 1024 + 255) / 256, NLAYER), 256, 0, stream>>>(
      in_proj, inpbf, 768, 1000, 768, 1024, (long)HDIM * 1000, 768 * 1024);
  convert_wT<<<dim3((128 * 512 + 255) / 256, NLAYER), 256, 0, stream>>>(
      x_proj, xpbf, 500, 80, 512, 128, (long)DI * 80, 128 * 512);
  convert_wT<<<dim3((512 * 64 + 255) / 256, NLAYER), 256, 0, stream>>>(
      dt_w, dtwbf, 48, 500, 64, 512, (long)RRANK * DI, 512 * 64);
  convert_wT<<<dim3((768 * 512 + 255) / 256, NLAYER), 256, 0, stream>>>(
      out_w, outwbf, 500, 768, 512, 768, (long)DI * HDIM, 768 * 512);

  // X = inputs @ W_down   (8192 x 768 x 4096)
  gemm_mfma<0><<<dim3(768 / 128, BL / 128), 256, 0, stream>>>(
      (const short*)Abf, (const short*)Wdbf, X, nullptr, nullptr, nullptr, BL,
      HDIM, INDIM, INDIM, INDIM, HDIM);

  for (int i = 0; i < NLAYER; ++i) {
    rmsnorm_kernel<<<BL, 256, 0, stream>>>(X, norm_w + i * HDIM, XNbf);
    // Uraw/Gate = split(XN @ in_proj[i]) bf16  (8192 x 1000 x 768)
    gemm_mfma<4><<<dim3(1024 / 128, BL / 128), 256, 0, stream>>>(
        (const short*)XNbf, (const short*)(inpbf + (long)i * 768 * 1024),
        nullptr, nullptr, Uraw, Gate, BL, 1000, HDIM, HDIM, HDIM, 0);
    // conv+silu -> Ubf (row-major) + Ut (transposed)
    conv_fused_kernel<<<dim3(16, 32, 8), 256, 0, stream>>>(Uraw, conv_w,
                                                           conv_b, Ubf, Ut, i);
    // SSM = U @ x_proj[i] (8192 x 80 x 512), fp32 + fused bf16 dt-slice
    gemm_mfma<5><<<dim3(1, BL / 128), 256, 0, stream>>>(
        (const short*)Ubf, (const short*)(xpbf + (long)i * 128 * 512), SSM,
        nullptr, (unsigned short*)SSMbf, nullptr, BL, 80, 512, 512, 512, 128);
    // DTt = softplus(SSM[:,:48] @ dt_w[i] + dt_b[i]) stored transposed
    gemm_mfma<3><<<dim3(512 / 128, BL / 128), 256, 0, stream>>>(
        (const short*)SSMbf, (const short*)(dtwbf + (long)i * 512 * 64), DTt,
        dt_b + i * DI, nullptr, nullptr, BL, DI, 64, 64, 64, 0);
    // chunked scan -> Yt
    scan_kernel<<<BATCH * DI, 256, 0, stream>>>(DTt, Ut, SSM, A_log, D_param,
                                                Yt, i);
    // Ybf = transpose(Yt) * silu(gate)
    y_gate_kernel<<<dim3(16, 32, 8), 256, 0, stream>>>(Yt, Gate, Ybf);
    // X += Y @ out_w[i]   (8192 x 768 x 512)
    gemm_mfma<1><<<dim3(768 / 128, BL / 128), 256, 0, stream>>>(
        (const short*)Ybf, (const short*)(outwbf + (long)i * 768 * 512), X,
        nullptr, nullptr, nullptr, BL, HDIM, 512, 512, 512, HDIM);
  }

  final_kernel<<<BATCH, 256, 0, stream>>>(X, norm_fw, W_cls, out);
}

// Round 6
// 1158.000 us; speedup vs baseline: 7.7558x; 1.0924x over previous
//
#include <hip/hip_runtime.h>
#include <hip/hip_bf16.h>

// Problem constants
#define BATCH 8
#define SEQL 1024
#define INDIM 4096
#define HDIM 768
#define DI 500
#define NSTATE 16
#define RRANK 48
#define KCONV 4
#define NLAYER 5
#define BL (BATCH * SEQL)  // 8192

typedef __attribute__((ext_vector_type(8))) short bf16x8;
typedef __attribute__((ext_vector_type(4))) float f32x4;

__device__ __forceinline__ void gl_lds16(const void* g, void* l) {
  __builtin_amdgcn_global_load_lds(
      (const __attribute__((address_space(1))) void*)g,
      (__attribute__((address_space(3))) void*)l, 16, 0, 0);
}

__device__ __forceinline__ unsigned short f2bf(float v) {
  return __hip_bfloat16_raw(__float2bfloat16(v)).x;
}
__device__ __forceinline__ float bf2f(unsigned short h) {
  unsigned int u = ((unsigned int)h) << 16;
  float f;
  memcpy(&f, &u, 4);
  return f;
}

// ---------------------------------------------------------------------------
// bf16 MFMA GEMM: C(M,N) fp32 = A(M,K)bf16 @ Bt(N,K)bf16^T  [+ epilogue]
// 128x128 tile, BK=32, 256 threads = 4 waves (2x2 of 64x64).
// 3-buffer LDS pipeline with counted vmcnt(4) + raw s_barrier (loads stay in
// flight across barriers; never drains to 0 in the main loop). Chunk-XOR
// swizzle (both-sides with global_load_lds) keeps ds_read conflict-free.
// Bijective XCD swizzle on the flat block id (all grids % 8 == 0): each XCD
// gets a contiguous chunk of tiles -> A-panel + B-weight L2 residency.
// EPI 0: store fp32
// EPI 1: C += (residual accumulate)
// EPI 3: softplus(v+bias[col]) stored TRANSPOSED fp32 to C=[b][col][t]
// EPI 4: bf16 split store: col<500 -> D0[row][col]; else D1[row][col-500]
// EPI 5: fp32 store (col<N) + bf16 D0[row][64] = (col<48 ? v : 0)
// ---------------------------------------------------------------------------
template <int EPI>
__global__ __launch_bounds__(256) void gemm_mfma(
    const short* __restrict__ A, const short* __restrict__ Bt,
    float* __restrict__ C, const float* __restrict__ bias,
    unsigned short* __restrict__ D0, unsigned short* __restrict__ D1,
    int M, int N, int K, int lda, int ldb, int ldc) {
  __shared__ short As[3][128 * 32];
  __shared__ short Bs[3][128 * 32];
  const int tid = threadIdx.x;
  const int w = tid >> 6, lane = tid & 63;

  // XCD-aware bijective swizzle (nwg divisible by 8 for all our launches)
  const int gx = gridDim.x;
  const int nwg = gx * gridDim.y;
  int flat = blockIdx.y * gx + blockIdx.x;
  flat = (flat & 7) * (nwg >> 3) + (flat >> 3);
  const int m0 = (flat / gx) * 128, n0 = (flat % gx) * 128;

  const int wr = w >> 1, wc = w & 1;
  f32x4 acc[4][4] = {};

  const int srow = tid >> 2;  // tile row 0..63 (each half)
  const int cpos = tid & 3;   // 16B chunk slot in LDS
  // pre-swizzle: this LDS slot receives data[row][cpos ^ ((row>>1)&3)]
  const int sc = (cpos ^ ((srow >> 1) & 3)) * 8;
  const short* ga0 = A + (size_t)(m0 + srow) * lda + sc;
  const short* ga1 = A + (size_t)(m0 + 64 + srow) * lda + sc;
  const short* gb0 = Bt + (size_t)(n0 + srow) * ldb + sc;
  const short* gb1 = Bt + (size_t)(n0 + 64 + srow) * ldb + sc;
  const int lr = lane & 15, kb = lane >> 4;
  const int kbx = (kb ^ ((lr >> 1) & 3)) * 8;  // reader-side XOR'd chunk

  auto stage = [&](int buf, int k0) {
    gl_lds16(ga0 + k0, &As[buf][w * 512]);
    gl_lds16(ga1 + k0, &As[buf][2048 + w * 512]);
    gl_lds16(gb0 + k0, &Bs[buf][w * 512]);
    gl_lds16(gb1 + k0, &Bs[buf][2048 + w * 512]);
  };
  auto compute = [&](int buf) {
    bf16x8 af[4], bfr[4];
#pragma unroll
    for (int i = 0; i < 4; ++i) {
      af[i] = *(const bf16x8*)&As[buf][(wr * 64 + i * 16 + lr) * 32 + kbx];
      bfr[i] = *(const bf16x8*)&Bs[buf][(wc * 64 + i * 16 + lr) * 32 + kbx];
    }
#pragma unroll
    for (int i = 0; i < 4; ++i)
#pragma unroll
      for (int j = 0; j < 4; ++j)
        acc[i][j] = __builtin_amdgcn_mfma_f32_16x16x32_bf16(af[i], bfr[j],
                                                            acc[i][j], 0, 0, 0);
  };

  const int nk = K >> 5;
  stage(0, 0);
  if (nk > 1) stage(1, 32);
  int cur = 0;
  for (int t = 0; t < nk; ++t) {
    // wait for tile t only (tile t+1 stays in flight); all-waves via barrier
    if (t + 1 < nk)
      asm volatile("s_waitcnt vmcnt(4)" ::: "memory");
    else
      asm volatile("s_waitcnt vmcnt(0)" ::: "memory");
    __builtin_amdgcn_s_barrier();
    __builtin_amdgcn_sched_barrier(0);
    compute(cur);
    if (t + 2 < nk) {
      int nb = cur + 2;
      if (nb >= 3) nb -= 3;
      stage(nb, (t + 2) * 32);  // overwrites buf read at iter t-1: safe, all
                                // reads drained before this iter's barrier
    }
    ++cur;
    if (cur == 3) cur = 0;
  }

  // C/D layout (m89): col = lane&15, row = (lane>>4)*4 + reg
#pragma unroll
  for (int i = 0; i < 4; ++i) {
    const int row = m0 + wr * 64 + i * 16 + (lane >> 4) * 4;
#pragma unroll
    for (int j = 0; j < 4; ++j) {
      const int col = n0 + wc * 64 + j * 16 + (lane & 15);
      if (EPI == 3) {
        if (col < N) {
          float4 v4;
#pragma unroll
          for (int r = 0; r < 4; ++r) {
            float v = acc[i][j][r] + bias[col];
            ((float*)&v4)[r] = (v > 15.f) ? v : log1pf(expf(v));
          }
          const int bb = row >> 10, tt = row & 1023;
          *(float4*)&C[((size_t)bb * DI + col) * 1024 + tt] = v4;
        }
      } else if (EPI == 4) {
#pragma unroll
        for (int r = 0; r < 4; ++r) {
          unsigned short h = f2bf(acc[i][j][r]);
          size_t rr = (size_t)(row + r);
          if (col < DI)
            D0[rr * 512 + col] = h;
          else
            D1[rr * 512 + (col - DI)] = h;
        }
      } else if (EPI == 5) {
#pragma unroll
        for (int r = 0; r < 4; ++r) {
          float v = acc[i][j][r];
          size_t rr = (size_t)(row + r);
          if (col < N) C[rr * ldc + col] = v;
          if (col < 64) D0[rr * 64 + col] = f2bf(col < RRANK ? v : 0.f);
        }
      } else {
        if (col < N) {
#pragma unroll
          for (int r = 0; r < 4; ++r) {
            float v = acc[i][j][r];
            size_t idx = (size_t)(row + r) * ldc + col;
            if (EPI == 1) v += C[idx];
            C[idx] = v;
          }
        }
      }
    }
  }
}

// ---------------------------------------------------------------------------
// fp32 -> bf16 cast
// ---------------------------------------------------------------------------
__global__ __launch_bounds__(256) void convert_cast(
    const float* __restrict__ src, __hip_bfloat16* __restrict__ dst, long n) {
  long i = ((long)blockIdx.x * 256 + threadIdx.x) * 4;
  if (i >= n) return;
  float4 v = *(const float4*)(src + i);
  dst[i + 0] = __float2bfloat16(v.x);
  dst[i + 1] = __float2bfloat16(v.y);
  dst[i + 2] = __float2bfloat16(v.z);
  dst[i + 3] = __float2bfloat16(v.w);
}

// ---------------------------------------------------------------------------
// Weight convert + transpose + pad: src fp32 [K][N] -> dst bf16 [Npad][Kpad]
// grid.y = layer index
// ---------------------------------------------------------------------------
__global__ __launch_bounds__(256) void convert_wT(
    const float* __restrict__ src, __hip_bfloat16* __restrict__ dst, int K,
    int N, int Kpad, int Npad, long src_lstride, long dst_lstride) {
  int idx = blockIdx.x * 256 + threadIdx.x;
  int per = Kpad * Npad;
  if (idx >= per) return;
  const float* s = src + (long)blockIdx.y * src_lstride;
  __hip_bfloat16* d = dst + (long)blockIdx.y * dst_lstride;
  int n = idx / Kpad, k = idx % Kpad;
  float v = (k < K && n < N) ? s[(long)k * N + n] : 0.f;
  d[idx] = __float2bfloat16(v);
}

// ---------------------------------------------------------------------------
__device__ __forceinline__ float block_sum256(float v, float* sm) {
#pragma unroll
  for (int off = 32; off > 0; off >>= 1) v += __shfl_down(v, off, 64);
  int wid = threadIdx.x >> 6;
  if ((threadIdx.x & 63) == 0) sm[wid] = v;
  __syncthreads();
  float t = sm[0] + sm[1] + sm[2] + sm[3];
  __syncthreads();
  return t;
}

// ---------------------------------------------------------------------------
__global__ __launch_bounds__(256) void rmsnorm_kernel(
    const float* __restrict__ X, const float* __restrict__ w,
    __hip_bfloat16* __restrict__ XN) {
  __shared__ float sm[4];
  const long row = blockIdx.x;
  const float* x = X + row * HDIM;
  float vals[3];
  float s = 0.f;
#pragma unroll
  for (int j = 0; j < 3; ++j) {
    vals[j] = x[threadIdx.x + j * 256];
    s += vals[j] * vals[j];
  }
  float tot = block_sum256(s, sm);
  float scale = rsqrtf(tot / (float)HDIM + 1e-5f);
#pragma unroll
  for (int j = 0; j < 3; ++j) {
    int c = threadIdx.x + j * 256;
    XN[row * HDIM + c] = __float2bfloat16(vals[j] * scale * w[c]);
  }
}

// ---------------------------------------------------------------------------
// Fused: causal depthwise conv(K=4)+SiLU reading Uraw bf16 [8192][512];
// writes Ubf [row][512] AND Ut [8][512][1024] (transposed) from one LDS tile.
// ---------------------------------------------------------------------------
__global__ __launch_bounds__(256) void conv_fused_kernel(
    const unsigned short* __restrict__ Uraw, const float* __restrict__ cw,
    const float* __restrict__ cb, unsigned short* __restrict__ Ubf,
    unsigned short* __restrict__ Ut, int layer) {
  __shared__ unsigned short tin[35][33];
  __shared__ unsigned short tout[32][33];
  const int d0 = blockIdx.x * 32, t0 = blockIdx.y * 32, b = blockIdx.z;
  const int tx = threadIdx.x & 31, ty = threadIdx.x >> 5;  // ty: 0..7
#pragma unroll
  for (int r = 0; r < 5; ++r) {
    int tr = ty + r * 8;
    if (tr < 35) {
      int t = t0 + tr - (KCONV - 1);
      tin[tr][tx] =
          (t >= 0) ? Uraw[((size_t)b * 1024 + t) * 512 + d0 + tx] : 0;
    }
  }
  __syncthreads();
  const int d = d0 + tx;
  float w0 = 0.f, w1 = 0.f, w2 = 0.f, w3 = 0.f, bias = 0.f;
  if (d < DI) {
    const float* w = cw + ((size_t)layer * DI + d) * KCONV;
    w0 = w[0]; w1 = w[1]; w2 = w[2]; w3 = w[3];
    bias = cb[layer * DI + d];
  }
#pragma unroll
  for (int r = 0; r < 4; ++r) {
    const int tt = ty + r * 8;
    unsigned short h = 0;
    if (d < DI) {
      float a = bias + w0 * bf2f(tin[tt][tx]) + w1 * bf2f(tin[tt + 1][tx]) +
                w2 * bf2f(tin[tt + 2][tx]) + w3 * bf2f(tin[tt + 3][tx]);
      h = f2bf(a / (1.f + expf(-a)));
    }
    tout[tt][tx] = h;
    Ubf[((size_t)b * 1024 + t0 + tt) * 512 + d] = h;
  }
  __syncthreads();
#pragma unroll
  for (int r = 0; r < 4; ++r) {
    const int dd = ty + r * 8;
    Ut[((size_t)b * 512 + d0 + dd) * 1024 + t0 + tx] = tout[tx][dd];
  }
}

// ---------------------------------------------------------------------------
// Yt [8][512][1024] bf16 -> Ybf [8192][512] with silu(gate), gate bf16
// ---------------------------------------------------------------------------
__global__ __launch_bounds__(256) void y_gate_kernel(
    const unsigned short* __restrict__ Yt, const unsigned short* __restrict__ G,
    unsigned short* __restrict__ Ybf) {
  __shared__ unsigned short tile[32][33];
  const int d0 = blockIdx.x * 32, t0 = blockIdx.y * 32, b = blockIdx.z;
  const int tx = threadIdx.x & 31, ty = threadIdx.x >> 5;
#pragma unroll
  for (int r = 0; r < 4; ++r) {
    int d = d0 + ty + r * 8;
    tile[ty + r * 8][tx] =
        (d < DI) ? Yt[((size_t)b * 512 + d) * 1024 + t0 + tx]
                 : (unsigned short)0;
  }
  __syncthreads();
#pragma unroll
  for (int r = 0; r < 4; ++r) {
    size_t row = (size_t)b * 1024 + t0 + ty + r * 8;
    int d = d0 + tx;
    float yv = 0.f;
    if (d < DI) {
      float y = bf2f(tile[tx][ty + r * 8]);
      float g = bf2f(G[row * 512 + d]);
      yv = y * (g / (1.f + expf(-g)));
    }
    Ybf[row * 512 + d] = f2bf(yv);
  }
}

// ---------------------------------------------------------------------------
// Chunked parallel SSM scan. Block = one (b,d); tid = chunk*16 + n.
// XCD-swizzled: each XCD handles exactly one batch index b (500 blocks) ->
// that b's SSM slice (512 KB) is XCD-L2 resident.
// ---------------------------------------------------------------------------
__global__ __launch_bounds__(256) void scan_kernel(
    const float* __restrict__ DTt, const unsigned short* __restrict__ Ut,
    const float* __restrict__ SSM, const float* __restrict__ A_log,
    const float* __restrict__ Dparam, unsigned short* __restrict__ Yt,
    int layer) {
  __shared__ float sdt[1040];
  __shared__ float su[1040];
  __shared__ float s_ap[16][17];
  __shared__ float s_h0[16][17];
  __shared__ float s_hi[16][17];
  const int orig = blockIdx.x;  // 4000
  const int blk = (orig & 7) * (BATCH * DI / 8) + (orig >> 3);
  const int b = blk / DI, d = blk % DI;
  const int tid = threadIdx.x;
  const int c = tid >> 4, n = tid & 15;

  const float* dtp = DTt + ((size_t)b * DI + d) * 1024;
  const unsigned short* up = Ut + ((size_t)b * 512 + d) * 1024;
#pragma unroll
  for (int k = 0; k < 4; ++k) {
    int x = tid + k * 256;
    sdt[x + (x >> 6)] = dtp[x];
    su[x + (x >> 6)] = bf2f(up[x]);
  }
  __syncthreads();

  const float An = -expf(A_log[((size_t)layer * DI + d) * NSTATE + n]);
  const float Dp = Dparam[layer * DI + d];
  const int t0 = c * 64;
  const int sb = t0 + c;
  const float* ssmB = SSM + ((size_t)b * 1024 + t0) * 128 + RRANK + n;

  float h = 0.f, ap = 1.f;
  for (int s = 0; s < 64; ++s) {
    float dt = sdt[sb + s];
    float a = __expf(dt * An);
    h = a * h + dt * su[sb + s] * ssmB[(size_t)s * 128];
    ap *= a;
  }
  s_ap[c][n] = ap;
  s_h0[c][n] = h;
  __syncthreads();

  if (tid < 16) {
    float hi = 0.f;
    for (int cc = 0; cc < 16; ++cc) {
      s_hi[cc][tid] = hi;
      hi = s_ap[cc][tid] * hi + s_h0[cc][tid];
    }
  }
  __syncthreads();

  h = s_hi[c][n];
  unsigned short* yp = Yt + ((size_t)b * 512 + d) * 1024 + t0;
  for (int s = 0; s < 64; ++s) {
    float dt = sdt[sb + s];
    float u = su[sb + s];
    float a = __expf(dt * An);
    h = a * h + dt * u * ssmB[(size_t)s * 128];
    float p = h * ssmB[(size_t)s * 128 + 16];
    p += __shfl_xor(p, 1, 64);
    p += __shfl_xor(p, 2, 64);
    p += __shfl_xor(p, 4, 64);
    p += __shfl_xor(p, 8, 64);
    if (n == 0) {
      float y = p + u * Dp;
      yp[s] = f2bf(y);
    }
  }
}

// ---------------------------------------------------------------------------
__global__ __launch_bounds__(256) void final_kernel(
    const float* __restrict__ X, const float* __restrict__ nfw,
    const float* __restrict__ Wcls, float* __restrict__ out) {
  __shared__ float sm[4];
  const int b = blockIdx.x;
  const long row = (long)b * SEQL + (SEQL - 1);
  const float* x = X + row * HDIM;
  float vals[3];
  float s = 0.f;
#pragma unroll
  for (int j = 0; j < 3; ++j) {
    vals[j] = x[threadIdx.x + j * 256];
    s += vals[j] * vals[j];
  }
  float tot = block_sum256(s, sm);
  float scale = rsqrtf(tot / (float)HDIM + 1e-5f);
  float dot = 0.f;
#pragma unroll
  for (int j = 0; j < 3; ++j) {
    int c = threadIdx.x + j * 256;
    dot += vals[j] * scale * nfw[c] * Wcls[c];
  }
  float td = block_sum256(dot, sm);
  if (threadIdx.x == 0) out[b] = td;
}

// ---------------------------------------------------------------------------
extern "C" void kernel_launch(void* const* d_in, const int* in_sizes, int n_in,
                              void* d_out, int out_size, void* d_ws,
                              size_t ws_size, hipStream_t stream) {
  const float* inputs  = (const float*)d_in[0];
  const float* W_down  = (const float*)d_in[1];
  const float* in_proj = (const float*)d_in[2];
  const float* conv_w  = (const float*)d_in[3];
  const float* conv_b  = (const float*)d_in[4];
  const float* x_proj  = (const float*)d_in[5];
  const float* dt_w    = (const float*)d_in[6];
  const float* dt_b    = (const float*)d_in[7];
  const float* A_log   = (const float*)d_in[8];
  const float* D_param = (const float*)d_in[9];
  const float* out_w   = (const float*)d_in[10];
  const float* norm_w  = (const float*)d_in[11];
  const float* norm_fw = (const float*)d_in[12];
  const float* W_cls   = (const float*)d_in[13];
  float* out = (float*)d_out;

  char* ws = (char*)d_ws;
  // --- init phase (0 .. 73,400,320): Abf + Wdbf ---
  __hip_bfloat16* Abf   = (__hip_bfloat16*)(ws + 0);         // 67108864
  __hip_bfloat16* Wdbf  = (__hip_bfloat16*)(ws + 67108864);  // -> 73400320
  // --- layer phase (aliases init region) ---
  __hip_bfloat16* XNbf  = (__hip_bfloat16*)(ws + 0);         // 12582912
  unsigned short* Yt    = (unsigned short*)(ws + 0);         // 8388608 (alias)
  float*          DTt   = (float*)(ws + 12582912);           // 16384000 -> 28966912
  unsigned short* Uraw  = (unsigned short*)(ws + 28966912);  // 8388608 -> 37355520
  unsigned short* Ybf   = (unsigned short*)(ws + 28966912);  // (alias, Uraw dead)
  unsigned short* Gate  = (unsigned short*)(ws + 37355520);  // 8388608 -> 45744128
  unsigned short* Ubf   = (unsigned short*)(ws + 45744128);  // 8388608 -> 54132736
  unsigned short* Ut    = (unsigned short*)(ws + 54132736);  // 8388608 -> 62521344
  float*          SSM   = (float*)(ws + 62521344);           // 4194304 -> 66715648
  __hip_bfloat16* SSMbf = (__hip_bfloat16*)(ws + 66715648);  // 1048576 -> 67764224
  // --- persistent ---
  float*          X     = (float*)(ws + 73400320);           // 25165824 -> 98566144
  __hip_bfloat16* inpbf = (__hip_bfloat16*)(ws + 98566144);  // 7864320 -> 106430464
  __hip_bfloat16* xpbf  = (__hip_bfloat16*)(ws + 106430464); // 655360  -> 107085824
  __hip_bfloat16* dtwbf = (__hip_bfloat16*)(ws + 107085824); // 327680  -> 107413504
  __hip_bfloat16* outwbf= (__hip_bfloat16*)(ws + 107413504); // 3932160 -> 111345664

  // --- init: conversions (all layers) ---
  convert_cast<<<(long)BL * 4096 / 4 / 256, 256, 0, stream>>>(inputs, Abf,
                                                              (long)BL * 4096);
  convert_wT<<<dim3((768 * 4096 + 255) / 256, 1), 256, 0, stream>>>(
      W_down, Wdbf, 4096, 768, 4096, 768, 0, 0);
  convert_wT<<<dim3((768 * 1024 + 255) / 256, NLAYER), 256, 0, stream>>>(
      in_proj, inpbf, 768, 1000, 768, 1024, (long)HDIM * 1000, 768 * 1024);
  convert_wT<<<dim3((128 * 512 + 255) / 256, NLAYER), 256, 0, stream>>>(
      x_proj, xpbf, 500, 80, 512, 128, (long)DI * 80, 128 * 512);
  convert_wT<<<dim3((512 * 64 + 255) / 256, NLAYER), 256, 0, stream>>>(
      dt_w, dtwbf, 48, 500, 64, 512, (long)RRANK * DI, 512 * 64);
  convert_wT<<<dim3((768 * 512 + 255) / 256, NLAYER), 256, 0, stream>>>(
      out_w, outwbf, 500, 768, 512, 768, (long)DI * HDIM, 768 * 512);

  // X = inputs @ W_down   (8192 x 768 x 4096)
  gemm_mfma<0><<<dim3(768 / 128, BL / 128), 256, 0, stream>>>(
      (const short*)Abf, (const short*)Wdbf, X, nullptr, nullptr, nullptr, BL,
      HDIM, INDIM, INDIM, INDIM, HDIM);

  for (int i = 0; i < NLAYER; ++i) {
    rmsnorm_kernel<<<BL, 256, 0, stream>>>(X, norm_w + i * HDIM, XNbf);
    // Uraw/Gate = split(XN @ in_proj[i]) bf16  (8192 x 1000 x 768)
    gemm_mfma<4><<<dim3(1024 / 128, BL / 128), 256, 0, stream>>>(
        (const short*)XNbf, (const short*)(inpbf + (long)i * 768 * 1024),
        nullptr, nullptr, Uraw, Gate, BL, 1000, HDIM, HDIM, HDIM, 0);
    // conv+silu -> Ubf (row-major) + Ut (transposed)
    conv_fused_kernel<<<dim3(16, 32, 8), 256, 0, stream>>>(Uraw, conv_w,
                                                           conv_b, Ubf, Ut, i);
    // SSM = U @ x_proj[i] (8192 x 80 x 512), fp32 + fused bf16 dt-slice
    gemm_mfma<5><<<dim3(1, BL / 128), 256, 0, stream>>>(
        (const short*)Ubf, (const short*)(xpbf + (long)i * 128 * 512), SSM,
        nullptr, (unsigned short*)SSMbf, nullptr, BL, 80, 512, 512, 512, 128);
    // DTt = softplus(SSM[:,:48] @ dt_w[i] + dt_b[i]) stored transposed
    gemm_mfma<3><<<dim3(512 / 128, BL / 128), 256, 0, stream>>>(
        (const short*)SSMbf, (const short*)(dtwbf + (long)i * 512 * 64), DTt,
        dt_b + i * DI, nullptr, nullptr, BL, DI, 64, 64, 64, 0);
    // chunked scan -> Yt
    scan_kernel<<<BATCH * DI, 256, 0, stream>>>(DTt, Ut, SSM, A_log, D_param,
                                                Yt, i);
    // Ybf = transpose(Yt) * silu(gate)
    y_gate_kernel<<<dim3(16, 32, 8), 256, 0, stream>>>(Yt, Gate, Ybf);
    // X += Y @ out_w[i]   (8192 x 768 x 512)
    gemm_mfma<1><<<dim3(768 / 128, BL / 128), 256, 0, stream>>>(
        (const short*)Ybf, (const short*)(outwbf + (long)i * 768 * 512), X,
        nullptr, nullptr, nullptr, BL, HDIM, 512, 512, 512, HDIM);
  }

  final_kernel<<<BATCH, 256, 0, stream>>>(X, norm_fw, W_cls, out);
}

// Round 7
// 1136.969 us; speedup vs baseline: 7.8993x; 1.0185x over previous
//
#include <hip/hip_runtime.h>
#include <hip/hip_bf16.h>

// Problem constants
#define BATCH 8
#define SEQL 1024
#define INDIM 4096
#define HDIM 768
#define DI 500
#define NSTATE 16
#define RRANK 48
#define KCONV 4
#define NLAYER 5
#define BL (BATCH * SEQL)  // 8192

typedef __attribute__((ext_vector_type(8))) short bf16x8;
typedef __attribute__((ext_vector_type(4))) float f32x4;

__device__ __forceinline__ void gl_lds16(const void* g, void* l) {
  __builtin_amdgcn_global_load_lds(
      (const __attribute__((address_space(1))) void*)g,
      (__attribute__((address_space(3))) void*)l, 16, 0, 0);
}

__device__ __forceinline__ unsigned short f2bf(float v) {
  return __hip_bfloat16_raw(__float2bfloat16(v)).x;
}
__device__ __forceinline__ float bf2f(unsigned short h) {
  unsigned int u = ((unsigned int)h) << 16;
  float f;
  memcpy(&f, &u, 4);
  return f;
}

// VALU 16-lane rotate-add (DPP row_ror) — replaces DS-pipe shfl_xor reduce
template <int CTRL>
__device__ __forceinline__ float ror_add(float x) {
  int r = __builtin_amdgcn_update_dpp(0, __float_as_int(x), CTRL, 0xf, 0xf,
                                      true);
  return x + __int_as_float(r);
}

// ---------------------------------------------------------------------------
// bf16 MFMA GEMM: C(M,N) fp32 = A(M,K)bf16 @ Bt(N,K)bf16^T  [+ epilogue]
// 128x128 tile, BK=32, 256 threads = 4 waves (2x2 of 64x64).
// 3-buffer LDS pipeline, counted vmcnt(4) + raw s_barrier, chunk-XOR LDS
// swizzle, bijective XCD block swizzle.
// EPI 0: store fp32
// EPI 1: C += (residual accumulate)
// EPI 3: softplus(v+bias[col]) stored TRANSPOSED fp32 to C=[b][col][t]
// EPI 4: bf16 split store: col<500 -> D0[row][col]; else D1[row][col-500]
// EPI 5: x_proj epi: D0[row][64] = bf16(col<48 ? v : 0);
//        BCpack C[row][32]: col 48..63 -> [2(col-48)], 64..79 -> [2(col-64)+1]
// ---------------------------------------------------------------------------
template <int EPI>
__global__ __launch_bounds__(256) void gemm_mfma(
    const short* __restrict__ A, const short* __restrict__ Bt,
    float* __restrict__ C, const float* __restrict__ bias,
    unsigned short* __restrict__ D0, unsigned short* __restrict__ D1,
    int M, int N, int K, int lda, int ldb, int ldc) {
  __shared__ short As[3][128 * 32];
  __shared__ short Bs[3][128 * 32];
  const int tid = threadIdx.x;
  const int w = tid >> 6, lane = tid & 63;

  // XCD-aware bijective swizzle (nwg divisible by 8 for all our launches)
  const int gx = gridDim.x;
  const int nwg = gx * gridDim.y;
  int flat = blockIdx.y * gx + blockIdx.x;
  flat = (flat & 7) * (nwg >> 3) + (flat >> 3);
  const int m0 = (flat / gx) * 128, n0 = (flat % gx) * 128;

  const int wr = w >> 1, wc = w & 1;
  f32x4 acc[4][4] = {};

  const int srow = tid >> 2;  // tile row 0..63 (each half)
  const int cpos = tid & 3;   // 16B chunk slot in LDS
  const int sc = (cpos ^ ((srow >> 1) & 3)) * 8;
  const short* ga0 = A + (size_t)(m0 + srow) * lda + sc;
  const short* ga1 = A + (size_t)(m0 + 64 + srow) * lda + sc;
  const short* gb0 = Bt + (size_t)(n0 + srow) * ldb + sc;
  const short* gb1 = Bt + (size_t)(n0 + 64 + srow) * ldb + sc;
  const int lr = lane & 15, kb = lane >> 4;
  const int kbx = (kb ^ ((lr >> 1) & 3)) * 8;  // reader-side XOR'd chunk

  auto stage = [&](int buf, int k0) {
    gl_lds16(ga0 + k0, &As[buf][w * 512]);
    gl_lds16(ga1 + k0, &As[buf][2048 + w * 512]);
    gl_lds16(gb0 + k0, &Bs[buf][w * 512]);
    gl_lds16(gb1 + k0, &Bs[buf][2048 + w * 512]);
  };
  auto compute = [&](int buf) {
    bf16x8 af[4], bfr[4];
#pragma unroll
    for (int i = 0; i < 4; ++i) {
      af[i] = *(const bf16x8*)&As[buf][(wr * 64 + i * 16 + lr) * 32 + kbx];
      bfr[i] = *(const bf16x8*)&Bs[buf][(wc * 64 + i * 16 + lr) * 32 + kbx];
    }
#pragma unroll
    for (int i = 0; i < 4; ++i)
#pragma unroll
      for (int j = 0; j < 4; ++j)
        acc[i][j] = __builtin_amdgcn_mfma_f32_16x16x32_bf16(af[i], bfr[j],
                                                            acc[i][j], 0, 0, 0);
  };

  const int nk = K >> 5;
  stage(0, 0);
  if (nk > 1) stage(1, 32);
  int cur = 0;
  for (int t = 0; t < nk; ++t) {
    if (t + 1 < nk)
      asm volatile("s_waitcnt vmcnt(4)" ::: "memory");
    else
      asm volatile("s_waitcnt vmcnt(0)" ::: "memory");
    __builtin_amdgcn_s_barrier();
    __builtin_amdgcn_sched_barrier(0);
    compute(cur);
    if (t + 2 < nk) {
      int nb = cur + 2;
      if (nb >= 3) nb -= 3;
      stage(nb, (t + 2) * 32);
    }
    ++cur;
    if (cur == 3) cur = 0;
  }

  // C/D layout (m89): col = lane&15, row = (lane>>4)*4 + reg
#pragma unroll
  for (int i = 0; i < 4; ++i) {
    const int row = m0 + wr * 64 + i * 16 + (lane >> 4) * 4;
#pragma unroll
    for (int j = 0; j < 4; ++j) {
      const int col = n0 + wc * 64 + j * 16 + (lane & 15);
      if (EPI == 3) {
        if (col < N) {
          float4 v4;
#pragma unroll
          for (int r = 0; r < 4; ++r) {
            float v = acc[i][j][r] + bias[col];
            ((float*)&v4)[r] = (v > 15.f) ? v : log1pf(expf(v));
          }
          const int bb = row >> 10, tt = row & 1023;
          *(float4*)&C[((size_t)bb * DI + col) * 1024 + tt] = v4;
        }
      } else if (EPI == 4) {
#pragma unroll
        for (int r = 0; r < 4; ++r) {
          unsigned short h = f2bf(acc[i][j][r]);
          size_t rr = (size_t)(row + r);
          if (col < DI)
            D0[rr * 512 + col] = h;
          else
            D1[rr * 512 + (col - DI)] = h;
        }
      } else if (EPI == 5) {
#pragma unroll
        for (int r = 0; r < 4; ++r) {
          float v = acc[i][j][r];
          size_t rr = (size_t)(row + r);
          if (col < 64) D0[rr * 64 + col] = f2bf(col < RRANK ? v : 0.f);
          if (col >= RRANK && col < 64) C[rr * 32 + 2 * (col - RRANK)] = v;
          if (col >= 64 && col < 80) C[rr * 32 + 2 * (col - 64) + 1] = v;
        }
      } else {
        if (col < N) {
#pragma unroll
          for (int r = 0; r < 4; ++r) {
            float v = acc[i][j][r];
            size_t idx = (size_t)(row + r) * ldc + col;
            if (EPI == 1) v += C[idx];
            C[idx] = v;
          }
        }
      }
    }
  }
}

// ---------------------------------------------------------------------------
// fp32 -> bf16 cast
// ---------------------------------------------------------------------------
__global__ __launch_bounds__(256) void convert_cast(
    const float* __restrict__ src, __hip_bfloat16* __restrict__ dst, long n) {
  long i = ((long)blockIdx.x * 256 + threadIdx.x) * 4;
  if (i >= n) return;
  float4 v = *(const float4*)(src + i);
  dst[i + 0] = __float2bfloat16(v.x);
  dst[i + 1] = __float2bfloat16(v.y);
  dst[i + 2] = __float2bfloat16(v.z);
  dst[i + 3] = __float2bfloat16(v.w);
}

// ---------------------------------------------------------------------------
// Weight convert + transpose + pad: src fp32 [K][N] -> dst bf16 [Npad][Kpad]
// ---------------------------------------------------------------------------
__global__ __launch_bounds__(256) void convert_wT(
    const float* __restrict__ src, __hip_bfloat16* __restrict__ dst, int K,
    int N, int Kpad, int Npad, long src_lstride, long dst_lstride) {
  int idx = blockIdx.x * 256 + threadIdx.x;
  int per = Kpad * Npad;
  if (idx >= per) return;
  const float* s = src + (long)blockIdx.y * src_lstride;
  __hip_bfloat16* d = dst + (long)blockIdx.y * dst_lstride;
  int n = idx / Kpad, k = idx % Kpad;
  float v = (k < K && n < N) ? s[(long)k * N + n] : 0.f;
  d[idx] = __float2bfloat16(v);
}

// ---------------------------------------------------------------------------
__device__ __forceinline__ float block_sum256(float v, float* sm) {
#pragma unroll
  for (int off = 32; off > 0; off >>= 1) v += __shfl_down(v, off, 64);
  int wid = threadIdx.x >> 6;
  if ((threadIdx.x & 63) == 0) sm[wid] = v;
  __syncthreads();
  float t = sm[0] + sm[1] + sm[2] + sm[3];
  __syncthreads();
  return t;
}

// ---------------------------------------------------------------------------
__global__ __launch_bounds__(256) void rmsnorm_kernel(
    const float* __restrict__ X, const float* __restrict__ w,
    __hip_bfloat16* __restrict__ XN) {
  __shared__ float sm[4];
  const long row = blockIdx.x;
  const float* x = X + row * HDIM;
  float vals[3];
  float s = 0.f;
#pragma unroll
  for (int j = 0; j < 3; ++j) {
    vals[j] = x[threadIdx.x + j * 256];
    s += vals[j] * vals[j];
  }
  float tot = block_sum256(s, sm);
  float scale = rsqrtf(tot / (float)HDIM + 1e-5f);
#pragma unroll
  for (int j = 0; j < 3; ++j) {
    int c = threadIdx.x + j * 256;
    XN[row * HDIM + c] = __float2bfloat16(vals[j] * scale * w[c]);
  }
}

// ---------------------------------------------------------------------------
// Fused: causal depthwise conv(K=4)+SiLU reading Uraw bf16 [8192][512];
// writes Ubf [row][512] AND Ut [8][512][1024] (transposed) from one LDS tile.
// ---------------------------------------------------------------------------
__global__ __launch_bounds__(256) void conv_fused_kernel(
    const unsigned short* __restrict__ Uraw, const float* __restrict__ cw,
    const float* __restrict__ cb, unsigned short* __restrict__ Ubf,
    unsigned short* __restrict__ Ut, int layer) {
  __shared__ unsigned short tin[35][33];
  __shared__ unsigned short tout[32][33];
  const int d0 = blockIdx.x * 32, t0 = blockIdx.y * 32, b = blockIdx.z;
  const int tx = threadIdx.x & 31, ty = threadIdx.x >> 5;  // ty: 0..7
#pragma unroll
  for (int r = 0; r < 5; ++r) {
    int tr = ty + r * 8;
    if (tr < 35) {
      int t = t0 + tr - (KCONV - 1);
      tin[tr][tx] =
          (t >= 0) ? Uraw[((size_t)b * 1024 + t) * 512 + d0 + tx] : 0;
    }
  }
  __syncthreads();
  const int d = d0 + tx;
  float w0 = 0.f, w1 = 0.f, w2 = 0.f, w3 = 0.f, bias = 0.f;
  if (d < DI) {
    const float* w = cw + ((size_t)layer * DI + d) * KCONV;
    w0 = w[0]; w1 = w[1]; w2 = w[2]; w3 = w[3];
    bias = cb[layer * DI + d];
  }
#pragma unroll
  for (int r = 0; r < 4; ++r) {
    const int tt = ty + r * 8;
    unsigned short h = 0;
    if (d < DI) {
      float a = bias + w0 * bf2f(tin[tt][tx]) + w1 * bf2f(tin[tt + 1][tx]) +
                w2 * bf2f(tin[tt + 2][tx]) + w3 * bf2f(tin[tt + 3][tx]);
      h = f2bf(a / (1.f + expf(-a)));
    }
    tout[tt][tx] = h;
    Ubf[((size_t)b * 1024 + t0 + tt) * 512 + d] = h;
  }
  __syncthreads();
#pragma unroll
  for (int r = 0; r < 4; ++r) {
    const int dd = ty + r * 8;
    Ut[((size_t)b * 512 + d0 + dd) * 1024 + t0 + tx] = tout[tx][dd];
  }
}

// ---------------------------------------------------------------------------
// Yt [8][512][1024] bf16 -> Ybf [8192][512] with silu(gate), gate bf16
// ---------------------------------------------------------------------------
__global__ __launch_bounds__(256) void y_gate_kernel(
    const unsigned short* __restrict__ Yt, const unsigned short* __restrict__ G,
    unsigned short* __restrict__ Ybf) {
  __shared__ unsigned short tile[32][33];
  const int d0 = blockIdx.x * 32, t0 = blockIdx.y * 32, b = blockIdx.z;
  const int tx = threadIdx.x & 31, ty = threadIdx.x >> 5;
#pragma unroll
  for (int r = 0; r < 4; ++r) {
    int d = d0 + ty + r * 8;
    tile[ty + r * 8][tx] =
        (d < DI) ? Yt[((size_t)b * 512 + d) * 1024 + t0 + tx]
                 : (unsigned short)0;
  }
  __syncthreads();
#pragma unroll
  for (int r = 0; r < 4; ++r) {
    size_t row = (size_t)b * 1024 + t0 + ty + r * 8;
    int d = d0 + tx;
    float yv = 0.f;
    if (d < DI) {
      float y = bf2f(tile[tx][ty + r * 8]);
      float g = bf2f(G[row * 512 + d]);
      yv = y * (g / (1.f + expf(-g)));
    }
    Ybf[row * 512 + d] = f2bf(yv);
  }
}

// ---------------------------------------------------------------------------
// Chunked parallel SSM scan v2. Block = one (b,d); 512 threads =
// 32 chunks x 32 steps; tid = chunk*16 + n.
// LDS: packed float2 {dt,u} (one ds_read_b64/step). B/C from BCpack
// [row][{B,C}x16] fp32 (one dwordx2/step, 128B/group coalesced).
// Reduce over 16 states via DPP row_ror adds (pure VALU, no DS pipe).
// XCD-swizzled: each XCD handles one batch index b.
// ---------------------------------------------------------------------------
__global__ __launch_bounds__(512) void scan_kernel(
    const float* __restrict__ DTt, const unsigned short* __restrict__ Ut,
    const float* __restrict__ BC, const float* __restrict__ A_log,
    const float* __restrict__ Dparam, unsigned short* __restrict__ Yt,
    int layer) {
  __shared__ float2 sdtu[1056];
  __shared__ float s_ap[32][17];
  __shared__ float s_h0[32][17];
  __shared__ float s_hi[32][17];
  const int orig = blockIdx.x;  // 4000
  const int blk = (orig & 7) * (BATCH * DI / 8) + (orig >> 3);
  const int b = blk / DI, d = blk % DI;
  const int tid = threadIdx.x;
  const int c = tid >> 4, n = tid & 15;

  const float* dtp = DTt + ((size_t)b * DI + d) * 1024;
  const unsigned short* up = Ut + ((size_t)b * 512 + d) * 1024;
#pragma unroll
  for (int k = 0; k < 2; ++k) {
    int x = tid + k * 512;
    sdtu[x + (x >> 5)] = make_float2(dtp[x], bf2f(up[x]));
  }
  __syncthreads();

  const float An2 =
      -expf(A_log[((size_t)layer * DI + d) * NSTATE + n]) * 1.44269504f;
  const float Dp = Dparam[layer * DI + d];
  const int t0 = c * 32;
  const float2* sb = sdtu + c * 33;  // skewed base
  const float2* bc = (const float2*)(BC + ((size_t)b * 1024 + t0) * 32) + n;

  // phase 1: local recurrence from h=0, track product of a
  float h = 0.f, ap = 1.f;
#pragma unroll 4
  for (int s = 0; s < 32; ++s) {
    float2 du = sb[s];
    float a = exp2f(du.x * An2);
    h = a * h + du.x * du.y * bc[s * 16].x;
    ap *= a;
  }
  s_ap[c][n] = ap;
  s_h0[c][n] = h;
  __syncthreads();

  // phase 2: serial combine over 32 chunks (16 threads)
  if (tid < 16) {
    float hi = 0.f;
    for (int cc = 0; cc < 32; ++cc) {
      s_hi[cc][tid] = hi;
      hi = s_ap[cc][tid] * hi + s_h0[cc][tid];
    }
  }
  __syncthreads();

  // phase 3: re-run with correct h_init, produce y
  h = s_hi[c][n];
  unsigned short* yp = Yt + ((size_t)b * 512 + d) * 1024 + t0;
#pragma unroll 4
  for (int s = 0; s < 32; ++s) {
    float2 du = sb[s];
    float2 v = bc[s * 16];
    float a = exp2f(du.x * An2);
    h = a * h + du.x * du.y * v.x;
    float p = h * v.y;
    p = ror_add<0x128>(p);  // row_ror:8
    p = ror_add<0x124>(p);  // row_ror:4
    p = ror_add<0x122>(p);  // row_ror:2
    p = ror_add<0x121>(p);  // row_ror:1
    if (n == 0) {
      yp[s] = f2bf(p + du.y * Dp);
    }
  }
}

// ---------------------------------------------------------------------------
__global__ __launch_bounds__(256) void final_kernel(
    const float* __restrict__ X, const float* __restrict__ nfw,
    const float* __restrict__ Wcls, float* __restrict__ out) {
  __shared__ float sm[4];
  const int b = blockIdx.x;
  const long row = (long)b * SEQL + (SEQL - 1);
  const float* x = X + row * HDIM;
  float vals[3];
  float s = 0.f;
#pragma unroll
  for (int j = 0; j < 3; ++j) {
    vals[j] = x[threadIdx.x + j * 256];
    s += vals[j] * vals[j];
  }
  float tot = block_sum256(s, sm);
  float scale = rsqrtf(tot / (float)HDIM + 1e-5f);
  float dot = 0.f;
#pragma unroll
  for (int j = 0; j < 3; ++j) {
    int c = threadIdx.x + j * 256;
    dot += vals[j] * scale * nfw[c] * Wcls[c];
  }
  float td = block_sum256(dot, sm);
  if (threadIdx.x == 0) out[b] = td;
}

// ---------------------------------------------------------------------------
extern "C" void kernel_launch(void* const* d_in, const int* in_sizes, int n_in,
                              void* d_out, int out_size, void* d_ws,
                              size_t ws_size, hipStream_t stream) {
  const float* inputs  = (const float*)d_in[0];
  const float* W_down  = (const float*)d_in[1];
  const float* in_proj = (const float*)d_in[2];
  const float* conv_w  = (const float*)d_in[3];
  const float* conv_b  = (const float*)d_in[4];
  const float* x_proj  = (const float*)d_in[5];
  const float* dt_w    = (const float*)d_in[6];
  const float* dt_b    = (const float*)d_in[7];
  const float* A_log   = (const float*)d_in[8];
  const float* D_param = (const float*)d_in[9];
  const float* out_w   = (const float*)d_in[10];
  const float* norm_w  = (const float*)d_in[11];
  const float* norm_fw = (const float*)d_in[12];
  const float* W_cls   = (const float*)d_in[13];
  float* out = (float*)d_out;

  char* ws = (char*)d_ws;
  // --- init phase (0 .. 73,400,320): Abf + Wdbf ---
  __hip_bfloat16* Abf   = (__hip_bfloat16*)(ws + 0);         // 67108864
  __hip_bfloat16* Wdbf  = (__hip_bfloat16*)(ws + 67108864);  // -> 73400320
  // --- layer phase (aliases init region) ---
  __hip_bfloat16* XNbf  = (__hip_bfloat16*)(ws + 0);         // 12582912
  unsigned short* Yt    = (unsigned short*)(ws + 0);         // 8388608 (alias)
  float*          DTt   = (float*)(ws + 12582912);           // 16384000 -> 28966912
  unsigned short* Uraw  = (unsigned short*)(ws + 28966912);  // 8388608 -> 37355520
  unsigned short* Ybf   = (unsigned short*)(ws + 28966912);  // (alias, Uraw dead)
  unsigned short* Gate  = (unsigned short*)(ws + 37355520);  // 8388608 -> 45744128
  unsigned short* Ubf   = (unsigned short*)(ws + 45744128);  // 8388608 -> 54132736
  unsigned short* Ut    = (unsigned short*)(ws + 54132736);  // 8388608 -> 62521344
  float*          BC    = (float*)(ws + 62521344);           // 1048576 -> 63569920
  __hip_bfloat16* SSMbf = (__hip_bfloat16*)(ws + 66715648);  // 1048576 -> 67764224
  // --- persistent ---
  float*          X     = (float*)(ws + 73400320);           // 25165824 -> 98566144
  __hip_bfloat16* inpbf = (__hip_bfloat16*)(ws + 98566144);  // 7864320 -> 106430464
  __hip_bfloat16* xpbf  = (__hip_bfloat16*)(ws + 106430464); // 655360  -> 107085824
  __hip_bfloat16* dtwbf = (__hip_bfloat16*)(ws + 107085824); // 327680  -> 107413504
  __hip_bfloat16* outwbf= (__hip_bfloat16*)(ws + 107413504); // 3932160 -> 111345664

  // --- init: conversions (all layers) ---
  convert_cast<<<(long)BL * 4096 / 4 / 256, 256, 0, stream>>>(inputs, Abf,
                                                              (long)BL * 4096);
  convert_wT<<<dim3((768 * 4096 + 255) / 256, 1), 256, 0, stream>>>(
      W_down, Wdbf, 4096, 768, 4096, 768, 0, 0);
  convert_wT<<<dim3((768 * 1024 + 255) / 256, NLAYER), 256, 0, stream>>>(
      in_proj, inpbf, 768, 1000, 768, 1024, (long)HDIM * 1000, 768 * 1024);
  convert_wT<<<dim3((128 * 512 + 255) / 256, NLAYER), 256, 0, stream>>>(
      x_proj, xpbf, 500, 80, 512, 128, (long)DI * 80, 128 * 512);
  convert_wT<<<dim3((512 * 64 + 255) / 256, NLAYER), 256, 0, stream>>>(
      dt_w, dtwbf, 48, 500, 64, 512, (long)RRANK * DI, 512 * 64);
  convert_wT<<<dim3((768 * 512 + 255) / 256, NLAYER), 256, 0, stream>>>(
      out_w, outwbf, 500, 768, 512, 768, (long)DI * HDIM, 768 * 512);

  // X = inputs @ W_down   (8192 x 768 x 4096)
  gemm_mfma<0><<<dim3(768 / 128, BL / 128), 256, 0, stream>>>(
      (const short*)Abf, (const short*)Wdbf, X, nullptr, nullptr, nullptr, BL,
      HDIM, INDIM, INDIM, INDIM, HDIM);

  for (int i = 0; i < NLAYER; ++i) {
    rmsnorm_kernel<<<BL, 256, 0, stream>>>(X, norm_w + i * HDIM, XNbf);
    // Uraw/Gate = split(XN @ in_proj[i]) bf16  (8192 x 1000 x 768)
    gemm_mfma<4><<<dim3(1024 / 128, BL / 128), 256, 0, stream>>>(
        (const short*)XNbf, (const short*)(inpbf + (long)i * 768 * 1024),
        nullptr, nullptr, Uraw, Gate, BL, 1000, HDIM, HDIM, HDIM, 0);
    // conv+silu -> Ubf (row-major) + Ut (transposed)
    conv_fused_kernel<<<dim3(16, 32, 8), 256, 0, stream>>>(Uraw, conv_w,
                                                           conv_b, Ubf, Ut, i);
    // x_proj GEMM (8192 x 80 x 512): SSMbf dt-slice bf16 + BCpack fp32
    gemm_mfma<5><<<dim3(1, BL / 128), 256, 0, stream>>>(
        (const short*)Ubf, (const short*)(xpbf + (long)i * 128 * 512), BC,
        nullptr, (unsigned short*)SSMbf, nullptr, BL, 80, 512, 512, 512, 0);
    // DTt = softplus(SSM[:,:48] @ dt_w[i] + dt_b[i]) stored transposed
    gemm_mfma<3><<<dim3(512 / 128, BL / 128), 256, 0, stream>>>(
        (const short*)SSMbf, (const short*)(dtwbf + (long)i * 512 * 64), DTt,
        dt_b + i * DI, nullptr, nullptr, BL, DI, 64, 64, 64, 0);
    // chunked scan v2 -> Yt
    scan_kernel<<<BATCH * DI, 512, 0, stream>>>(DTt, Ut, BC, A_log, D_param,
                                                Yt, i);
    // Ybf = transpose(Yt) * silu(gate)
    y_gate_kernel<<<dim3(16, 32, 8), 256, 0, stream>>>(Yt, Gate, Ybf);
    // X += Y @ out_w[i]   (8192 x 768 x 512)
    gemm_mfma<1><<<dim3(768 / 128, BL / 128), 256, 0, stream>>>(
        (const short*)Ybf, (const short*)(outwbf + (long)i * 768 * 512), X,
        nullptr, nullptr, nullptr, BL, HDIM, 512, 512, 512, HDIM);
  }

  final_kernel<<<BATCH, 256, 0, stream>>>(X, norm_fw, W_cls, out);
}